// Round 6
// baseline (30.397 us; speedup 1.0000x reference)
//
#include <hip/hip_runtime.h>
#include <hip/hip_bf16.h>

#define ALPHA 0.2f
constexpr int B = 8, K = 256, F = 64, E = 128;   // E = 2*F

// ---------------------------------------------------------------------------
// Workspace floats:
//   u   [B*K][E]                                               262144
//   vT  float4-transposed v: f4-idx (b*32+e4)*K + k, comp e&3  262144
//   c   [B*K] = sum_e a_e*v, d [B*K] = sum_e a_e*u             2048 + 2048
// (no packed weights — k1/k2 read lin_w / fc_w raw through L1)
// ---------------------------------------------------------------------------

// k1: 512 blocks x 256 threads; thread (e = t>>1, fh = t&1) computes the
// fh-half of the F-dot for 4 rows; pair lanes combine via shfl_xor(1).
__global__ __launch_bounds__(256) void gat_k1(
    const float* __restrict__ x, const float* __restrict__ lin_w,
    const float* __restrict__ lin_b, const float* __restrict__ a,
    float* __restrict__ u, float* __restrict__ vT,
    float* __restrict__ c, float* __restrict__ d)
{
    const int t = threadIdx.x;
    const int wave = t >> 6, lane = t & 63;
    const int row0 = blockIdx.x * 4;
    const int e = t >> 1, fh = t & 1;
    const int b = row0 >> 8;

    __shared__ float xs[4 * F];
    __shared__ float redA[4][8];

    xs[t] = x[row0 * F + t];
    __syncthreads();

    // each lane: its 32-float half-row of w1 and w2 (one L1 line each)
    const float* w1p = lin_w + e * (2 * F) + fh * 32;
    const float* w2p = w1p + F;
    float acc1[4] = {0, 0, 0, 0}, acc2[4] = {0, 0, 0, 0};
#pragma unroll
    for (int f4 = 0; f4 < 8; ++f4) {
        float4 w1v = *(const float4*)(w1p + f4 * 4);
        float4 w2v = *(const float4*)(w2p + f4 * 4);
#pragma unroll
        for (int r = 0; r < 4; ++r) {
            float4 xv = *(const float4*)&xs[r * F + fh * 32 + f4 * 4];
            acc1[r] = fmaf(w1v.x, xv.x, acc1[r]); acc1[r] = fmaf(w1v.y, xv.y, acc1[r]);
            acc1[r] = fmaf(w1v.z, xv.z, acc1[r]); acc1[r] = fmaf(w1v.w, xv.w, acc1[r]);
            acc2[r] = fmaf(w2v.x, xv.x, acc2[r]); acc2[r] = fmaf(w2v.y, xv.y, acc2[r]);
            acc2[r] = fmaf(w2v.z, xv.z, acc2[r]); acc2[r] = fmaf(w2v.w, xv.w, acc2[r]);
        }
    }
    // combine f-halves (both pair lanes end up with the full dot)
#pragma unroll
    for (int r = 0; r < 4; ++r) {
        acc1[r] += __shfl_xor(acc1[r], 1);
        acc2[r] += __shfl_xor(acc2[r], 1);
    }

    const float bb = lin_b[e], av = a[e];
    float uu[4];
    float vals[8];
#pragma unroll
    for (int r = 0; r < 4; ++r) {
        uu[r] = acc1[r] + bb;
        vals[r]     = av * acc2[r];          // c partial (e counted twice/pair)
        vals[4 + r] = av * uu[r];            // d partial
    }

    if (fh == 0) {                           // one lane per e writes
#pragma unroll
        for (int r = 0; r < 4; ++r) {
            const int rr = row0 + r;
            u[rr * E + e] = uu[r];
            vT[((b * 32 + (e >> 2)) * K + (rr & (K - 1))) * 4 + (e & 3)] = acc2[r];
        }
    }

#pragma unroll
    for (int off = 32; off; off >>= 1) {
#pragma unroll
        for (int q = 0; q < 8; ++q) vals[q] += __shfl_xor(vals[q], off);
    }
    if (lane == 0) {
#pragma unroll
        for (int q = 0; q < 8; ++q) redA[wave][q] = vals[q];
    }
    __syncthreads();
    if (t < 8) {
        const int r = t & 3, isd = t >> 2;
        // 0.5: every e appears in two lanes of its wave
        float val = 0.5f * (redA[0][t] + redA[1][t] + redA[2][t] + redA[3][t]);
        if (isd == 0) c[row0 + r] = val; else d[row0 + r] = val;
    }
}

// k2: 512 blocks x 256 threads; block = (b, 4 i-rows); thread t = j for e-loop.
__global__ __launch_bounds__(256) void gat_k2(
    const float* __restrict__ x, const float* __restrict__ a,
    const float* __restrict__ att_bias, const float* __restrict__ fc_w,
    const float* __restrict__ fc_b, const float* __restrict__ u,
    const float4* __restrict__ vT4, const float* __restrict__ c,
    const float* __restrict__ d, float* __restrict__ out)
{
    const int blk = blockIdx.x;
    const int b = blk >> 6;
    const int i0 = (blk & 63) * 4;
    const int t = threadIdx.x;               // j
    const int wave = t >> 6, lane = t & 63;

    __shared__ float4 us4[4 * 32];           // u rows i0..i0+3
    __shared__ float aas[E];                 // 0.4 * a
    __shared__ float ps[4 * 257];
    __shared__ float4 hpart[4][4][16];
    __shared__ float4 h4s[4][16];
    __shared__ float redm[4][4], reds[4][4];

    // ---- preamble ----
    if (t < 128) {
        const float4* usrc = (const float4*)(u + (size_t)(b * K + i0) * E);
        us4[t] = usrc[t];
        aas[t] = 0.4f * a[t];
    }
    const float cj = c[b * K + t];
    const float d0 = d[b * K + i0],     d1 = d[b * K + i0 + 1];
    const float d2 = d[b * K + i0 + 2], d3 = d[b * K + i0 + 3];
    const float ab0 = att_bias[(i0 + 0) * K + t];
    const float ab1 = att_bias[(i0 + 1) * K + t];
    const float ab2 = att_bias[(i0 + 2) * K + t];
    const float ab3 = att_bias[(i0 + 3) * K + t];
    __syncthreads();

    // ---- e-loop: ej[i] = sum_e (0.4 a_e)|u_ie + v_je|, 1 global load/iter ----
    const float4* v4 = vT4 + (size_t)b * 32 * K + t;
    const float* us = (const float*)us4;
    float ej0 = 0.f, ej1 = 0.f, ej2 = 0.f, ej3 = 0.f;
#pragma unroll 8
    for (int e4 = 0; e4 < 32; ++e4) {
        float4 v  = v4[e4 * K];
        float4 aa = *(const float4*)&aas[e4 * 4];
        float4 u0 = *(const float4*)&us[0 * E + e4 * 4];
        float4 u1 = *(const float4*)&us[1 * E + e4 * 4];
        float4 u2 = *(const float4*)&us[2 * E + e4 * 4];
        float4 u3 = *(const float4*)&us[3 * E + e4 * 4];
        ej0 = fmaf(aa.x, fabsf(u0.x + v.x), ej0); ej0 = fmaf(aa.y, fabsf(u0.y + v.y), ej0);
        ej0 = fmaf(aa.z, fabsf(u0.z + v.z), ej0); ej0 = fmaf(aa.w, fabsf(u0.w + v.w), ej0);
        ej1 = fmaf(aa.x, fabsf(u1.x + v.x), ej1); ej1 = fmaf(aa.y, fabsf(u1.y + v.y), ej1);
        ej1 = fmaf(aa.z, fabsf(u1.z + v.z), ej1); ej1 = fmaf(aa.w, fabsf(u1.w + v.w), ej1);
        ej2 = fmaf(aa.x, fabsf(u2.x + v.x), ej2); ej2 = fmaf(aa.y, fabsf(u2.y + v.y), ej2);
        ej2 = fmaf(aa.z, fabsf(u2.z + v.z), ej2); ej2 = fmaf(aa.w, fabsf(u2.w + v.w), ej2);
        ej3 = fmaf(aa.x, fabsf(u3.x + v.x), ej3); ej3 = fmaf(aa.y, fabsf(u3.y + v.y), ej3);
        ej3 = fmaf(aa.z, fabsf(u3.z + v.z), ej3); ej3 = fmaf(aa.w, fabsf(u3.w + v.w), ej3);
    }
    float e0 = fmaf(0.6f, d0 + cj, ej0) + ab0;
    float e1 = fmaf(0.6f, d1 + cj, ej1) + ab1;
    float e2 = fmaf(0.6f, d2 + cj, ej2) + ab2;
    float e3 = fmaf(0.6f, d3 + cj, ej3) + ab3;

    // ---- softmax over j (4 rows) ----
    float m0 = e0, m1 = e1, m2 = e2, m3 = e3;
#pragma unroll
    for (int off = 32; off; off >>= 1) {
        m0 = fmaxf(m0, __shfl_xor(m0, off)); m1 = fmaxf(m1, __shfl_xor(m1, off));
        m2 = fmaxf(m2, __shfl_xor(m2, off)); m3 = fmaxf(m3, __shfl_xor(m3, off));
    }
    if (lane == 0) { redm[wave][0] = m0; redm[wave][1] = m1; redm[wave][2] = m2; redm[wave][3] = m3; }
    __syncthreads();
    m0 = fmaxf(fmaxf(redm[0][0], redm[1][0]), fmaxf(redm[2][0], redm[3][0]));
    m1 = fmaxf(fmaxf(redm[0][1], redm[1][1]), fmaxf(redm[2][1], redm[3][1]));
    m2 = fmaxf(fmaxf(redm[0][2], redm[1][2]), fmaxf(redm[2][2], redm[3][2]));
    m3 = fmaxf(fmaxf(redm[0][3], redm[1][3]), fmaxf(redm[2][3], redm[3][3]));
    float x0 = __expf(e0 - m0), x1 = __expf(e1 - m1), x2 = __expf(e2 - m2), x3 = __expf(e3 - m3);
    float s0 = x0, s1 = x1, s2 = x2, s3 = x3;
#pragma unroll
    for (int off = 32; off; off >>= 1) {
        s0 += __shfl_xor(s0, off); s1 += __shfl_xor(s1, off);
        s2 += __shfl_xor(s2, off); s3 += __shfl_xor(s3, off);
    }
    if (lane == 0) { reds[wave][0] = s0; reds[wave][1] = s1; reds[wave][2] = s2; reds[wave][3] = s3; }
    __syncthreads();
    s0 = reds[0][0] + reds[1][0] + reds[2][0] + reds[3][0];
    s1 = reds[0][1] + reds[1][1] + reds[2][1] + reds[3][1];
    s2 = reds[0][2] + reds[1][2] + reds[2][2] + reds[3][2];
    s3 = reds[0][3] + reds[1][3] + reds[2][3] + reds[3][3];
    ps[0 * 257 + t] = x0 / s0;
    ps[1 * 257 + t] = x1 / s1;
    ps[2 * 257 + t] = x2 / s2;
    ps[3 * 257 + t] = x3 / s3;
    __syncthreads();

    // ---- h-loop: thread = (jg, fq); each x float4 loaded ONCE, feeds 4 rows ----
    {
        const int jg = t >> 4, fq = t & 15;
        const float4* xb4 = (const float4*)x + (size_t)b * K * 16 + fq;
        float4 h0 = make_float4(0,0,0,0), h1 = h0, h2 = h0, h3 = h0;
#pragma unroll 4
        for (int jj = 0; jj < 16; ++jj) {
            int j = jg * 16 + jj;
            float4 xv = xb4[(size_t)j * 16];
            float p0 = ps[0 * 257 + j], p1 = ps[1 * 257 + j];
            float p2 = ps[2 * 257 + j], p3 = ps[3 * 257 + j];
            h0.x = fmaf(p0, xv.x, h0.x); h0.y = fmaf(p0, xv.y, h0.y);
            h0.z = fmaf(p0, xv.z, h0.z); h0.w = fmaf(p0, xv.w, h0.w);
            h1.x = fmaf(p1, xv.x, h1.x); h1.y = fmaf(p1, xv.y, h1.y);
            h1.z = fmaf(p1, xv.z, h1.z); h1.w = fmaf(p1, xv.w, h1.w);
            h2.x = fmaf(p2, xv.x, h2.x); h2.y = fmaf(p2, xv.y, h2.y);
            h2.z = fmaf(p2, xv.z, h2.z); h2.w = fmaf(p2, xv.w, h2.w);
            h3.x = fmaf(p3, xv.x, h3.x); h3.y = fmaf(p3, xv.y, h3.y);
            h3.z = fmaf(p3, xv.z, h3.z); h3.w = fmaf(p3, xv.w, h3.w);
        }
#pragma unroll
        for (int off = 16; off <= 32; off <<= 1) {
            h0.x += __shfl_xor(h0.x, off); h0.y += __shfl_xor(h0.y, off);
            h0.z += __shfl_xor(h0.z, off); h0.w += __shfl_xor(h0.w, off);
            h1.x += __shfl_xor(h1.x, off); h1.y += __shfl_xor(h1.y, off);
            h1.z += __shfl_xor(h1.z, off); h1.w += __shfl_xor(h1.w, off);
            h2.x += __shfl_xor(h2.x, off); h2.y += __shfl_xor(h2.y, off);
            h2.z += __shfl_xor(h2.z, off); h2.w += __shfl_xor(h2.w, off);
            h3.x += __shfl_xor(h3.x, off); h3.y += __shfl_xor(h3.y, off);
            h3.z += __shfl_xor(h3.z, off); h3.w += __shfl_xor(h3.w, off);
        }
        if (lane < 16) {
            hpart[wave][0][lane] = h0; hpart[wave][1][lane] = h1;
            hpart[wave][2][lane] = h2; hpart[wave][3][lane] = h3;
        }
    }
    __syncthreads();
    if (t < 64) {
        const int i = t >> 4, f4 = t & 15;
        float4 A = hpart[0][i][f4], Bq = hpart[1][i][f4];
        float4 C = hpart[2][i][f4], D = hpart[3][i][f4];
        float4 hv;
        hv.x = A.x + Bq.x + C.x + D.x; hv.y = A.y + Bq.y + C.y + D.y;
        hv.z = A.z + Bq.z + C.z + D.z; hv.w = A.w + Bq.w + C.w + D.w;
        hv.x = 1.f / (1.f + __expf(-hv.x)); hv.y = 1.f / (1.f + __expf(-hv.y));
        hv.z = 1.f / (1.f + __expf(-hv.z)); hv.w = 1.f / (1.f + __expf(-hv.w));
        h4s[i][f4] = hv;
    }
    __syncthreads();

    // ---- fc epilogue: thread = (i=wave, o=lane); raw fc_w rows via L1 ----
    {
        const float4* wrow = (const float4*)(fc_w + lane * F);
        float acc = 0.f;
#pragma unroll
        for (int f4 = 0; f4 < 16; ++f4) {
            float4 hv = h4s[wave][f4];       // LDS broadcast
            float4 wv = wrow[f4];            // own row, L1-resident
            acc = fmaf(hv.x, wv.x, acc); acc = fmaf(hv.y, wv.y, acc);
            acc = fmaf(hv.z, wv.z, acc); acc = fmaf(hv.w, wv.w, acc);
        }
        out[(b * K + i0 + wave) * F + lane] = acc + fc_b[lane];
    }
}

extern "C" void kernel_launch(void* const* d_in, const int* in_sizes, int n_in,
                              void* d_out, int out_size, void* d_ws, size_t ws_size,
                              hipStream_t stream) {
    const float* x        = (const float*)d_in[0];
    const float* lin_w    = (const float*)d_in[1];
    const float* lin_b    = (const float*)d_in[2];
    const float* a        = (const float*)d_in[3];
    const float* att_bias = (const float*)d_in[4];
    const float* fc_w     = (const float*)d_in[5];
    const float* fc_b     = (const float*)d_in[6];
    float* out = (float*)d_out;

    float* u   = (float*)d_ws;                     // 262144 floats
    float* vT  = u + B * K * E;                    // 262144
    float* c   = vT + B * K * E;                   // 2048
    float* d   = c + B * K;                        // 2048

    gat_k1<<<B * K / 4, 256, 0, stream>>>(x, lin_w, lin_b, a, u, vT, c, d);
    gat_k2<<<B * K / 4, 256, 0, stream>>>(x, a, att_bias, fc_w, fc_b, u,
                                          (const float4*)vT, c, d, out);
}

// Round 7
// 28.239 us; speedup vs baseline: 1.0764x; 1.0764x over previous
//
#include <hip/hip_runtime.h>
#include <hip/hip_bf16.h>

#define ALPHA 0.2f
constexpr int B = 8, K = 256, F = 64, E = 128;   // E = 2*F

// ---------------------------------------------------------------------------
// Workspace floats:
//   u   [B*K][E]                                               262144
//   vT  float4-transposed v: f4-idx (b*32+e4)*K + k, comp e&3  262144
//   c   [B*K] = sum_e a_e*v, d [B*K] = sum_e a_e*u             2048 + 2048
//   wq  float4 [32][128] packed lin_w                          16384 fl
//   fcp float4 [16][64]  packed fc_w                           4096 fl
// ---------------------------------------------------------------------------

__device__ __forceinline__ float term4(float4 aa, float4 uu, float4 vv, float acc) {
    acc = fmaf(aa.x, fabsf(uu.x + vv.x), acc);
    acc = fmaf(aa.y, fabsf(uu.y + vv.y), acc);
    acc = fmaf(aa.z, fabsf(uu.z + vv.z), acc);
    acc = fmaf(aa.w, fabsf(uu.w + vv.w), acc);
    return acc;
}

// k0: pack weights for coalesced access (20 blocks x 256)
__global__ __launch_bounds__(256) void gat_k0(
    const float* __restrict__ lin_w, const float* __restrict__ fc_w,
    float4* __restrict__ wq, float4* __restrict__ fcp)
{
    int idx = blockIdx.x * 256 + threadIdx.x;
    if (idx < 32 * E) {                       // lin_w -> wq
        int e = idx & (E - 1), f2 = idx >> 7;
        const float* r = lin_w + e * (2 * F) + 2 * f2;
        wq[f2 * E + e] = make_float4(r[0], r[1], r[F], r[F + 1]);
    } else {                                  // fc_w -> fcp
        int k = idx - 32 * E;
        int f4 = k >> 6, o = k & 63;
        const float* r = fc_w + o * F + f4 * 4;
        fcp[k] = make_float4(r[0], r[1], r[2], r[3]);
    }
}

// k1: 512 blocks x 256 threads; thread (e, rh) computes 2 rows -> 4 rows/block.
__global__ __launch_bounds__(256) void gat_k1(
    const float* __restrict__ x, const float4* __restrict__ wq,
    const float* __restrict__ lin_b, const float* __restrict__ a,
    float* __restrict__ u, float* __restrict__ vT,
    float* __restrict__ c, float* __restrict__ d)
{
    const int t = threadIdx.x;
    const int wave = t >> 6, lane = t & 63;
    const int row0 = blockIdx.x * 4;
    const int e = t & 127, rh = t >> 7;
    const int b = row0 >> 8;

    __shared__ float xs[4 * F];
    __shared__ float redA[4][4];

    xs[t] = x[row0 * F + t];
    __syncthreads();

    const float* xr0 = &xs[(rh * 2) * F];
    const float* xr1 = &xs[(rh * 2 + 1) * F];
    float a10 = 0.f, a11 = 0.f, a20 = 0.f, a21 = 0.f;
#pragma unroll
    for (int f2 = 0; f2 < 32; ++f2) {
        float4 w = wq[f2 * E + e];           // coalesced 16B/lane, L2-shared
        float x0 = xr0[2 * f2], x1 = xr0[2 * f2 + 1];
        float y0 = xr1[2 * f2], y1 = xr1[2 * f2 + 1];
        a10 = fmaf(w.x, x0, fmaf(w.y, x1, a10));
        a20 = fmaf(w.z, x0, fmaf(w.w, x1, a20));
        a11 = fmaf(w.x, y0, fmaf(w.y, y1, a11));
        a21 = fmaf(w.z, y0, fmaf(w.w, y1, a21));
    }
    const float bb = lin_b[e], av = a[e];
    const float u0 = a10 + bb, u1 = a11 + bb;
    const int r0 = row0 + rh * 2;
    u[r0 * E + e] = u0;
    u[(r0 + 1) * E + e] = u1;
    const int kk = r0 & (K - 1);
    float* vbase = vT + ((b * 32 + (e >> 2)) * K) * 4 + (e & 3);
    vbase[kk * 4] = a20;
    vbase[(kk + 1) * 4] = a21;

    float vals[4] = {av * a20, av * u0, av * a21, av * u1};  // c0,d0,c1,d1
#pragma unroll
    for (int off = 32; off; off >>= 1) {
#pragma unroll
        for (int q = 0; q < 4; ++q) vals[q] += __shfl_xor(vals[q], off);
    }
    if (lane == 0) {
        redA[wave][0] = vals[0]; redA[wave][1] = vals[1];
        redA[wave][2] = vals[2]; redA[wave][3] = vals[3];
    }
    __syncthreads();
    if (t < 8) {
        int r = t >> 1, w = t & 1;           // row 0..3, 0=c 1=d
        int wp = (r >> 1) * 2, q = (r & 1) * 2 + w;
        float val = redA[wp][q] + redA[wp + 1][q];
        if (w == 0) c[row0 + r] = val; else d[row0 + r] = val;
    }
}

// k2: 512 blocks x 256 threads; block = (b, 4 i-rows).
// e-loop: wave = e-quarter, lane = jj, thread tile = 4i x 4j -> every u/a
// float4 is DS-broadcast exactly once per block; partial ej combined in LDS.
__global__ __launch_bounds__(256) void gat_k2(
    const float* __restrict__ x, const float* __restrict__ a,
    const float* __restrict__ att_bias, const float4* __restrict__ fcp,
    const float* __restrict__ fc_b, const float* __restrict__ u,
    const float4* __restrict__ vT4, const float* __restrict__ c,
    const float* __restrict__ d, float* __restrict__ out)
{
    const int blk = blockIdx.x;
    const int b = blk >> 6;
    const int i0 = (blk & 63) * 4;
    const int t = threadIdx.x;
    const int wave = t >> 6, lane = t & 63;

    __shared__ float4 us4[4 * 32];           // u rows i0..i0+3
    __shared__ float4 aas4[32];              // 0.4 * a
    __shared__ float part[4][4][K];          // [eq][i][j] partial ej, 16 KB
    __shared__ float ps[4][K];               // softmax weights (float4-readable)
    __shared__ float4 hpart[4][4][16];
    __shared__ float4 h4s[4][16];
    __shared__ float redm[4][4], reds[4][4];

    // ---- preamble ----
    if (t < 128) {
        const float4* usrc = (const float4*)(u + (size_t)(b * K + i0) * E);
        us4[t] = usrc[t];
        ((float*)aas4)[t] = 0.4f * a[t];
    }
    const float cj = c[b * K + t];
    const float d0 = d[b * K + i0],     d1 = d[b * K + i0 + 1];
    const float d2 = d[b * K + i0 + 2], d3 = d[b * K + i0 + 3];
    const float ab0 = att_bias[(i0 + 0) * K + t];
    const float ab1 = att_bias[(i0 + 1) * K + t];
    const float ab2 = att_bias[(i0 + 2) * K + t];
    const float ab3 = att_bias[(i0 + 3) * K + t];
    __syncthreads();

    // ---- e-loop: wave eq handles e4 in [eq*8, eq*8+8); 4i x 4j per thread ----
    {
        const int eq = wave, jj = lane;
        const float4* v4 = vT4 + (size_t)b * 32 * K + (size_t)eq * 8 * K + jj;
        float ej[4][4];                      // [i][jq]
#pragma unroll
        for (int i = 0; i < 4; ++i)
#pragma unroll
            for (int q = 0; q < 4; ++q) ej[i][q] = 0.f;

#pragma unroll 2
        for (int it = 0; it < 8; ++it) {
            const int e4 = eq * 8 + it;
            float4 aa = aas4[e4];            // uniform (1 broadcast DS read)
            float4 uu0 = us4[0 * 32 + e4];
            float4 uu1 = us4[1 * 32 + e4];
            float4 uu2 = us4[2 * 32 + e4];
            float4 uu3 = us4[3 * 32 + e4];
            float4 vv0 = v4[it * K + 0 * 64];
            float4 vv1 = v4[it * K + 1 * 64];
            float4 vv2 = v4[it * K + 2 * 64];
            float4 vv3 = v4[it * K + 3 * 64];
            ej[0][0] = term4(aa, uu0, vv0, ej[0][0]); ej[0][1] = term4(aa, uu0, vv1, ej[0][1]);
            ej[0][2] = term4(aa, uu0, vv2, ej[0][2]); ej[0][3] = term4(aa, uu0, vv3, ej[0][3]);
            ej[1][0] = term4(aa, uu1, vv0, ej[1][0]); ej[1][1] = term4(aa, uu1, vv1, ej[1][1]);
            ej[1][2] = term4(aa, uu1, vv2, ej[1][2]); ej[1][3] = term4(aa, uu1, vv3, ej[1][3]);
            ej[2][0] = term4(aa, uu2, vv0, ej[2][0]); ej[2][1] = term4(aa, uu2, vv1, ej[2][1]);
            ej[2][2] = term4(aa, uu2, vv2, ej[2][2]); ej[2][3] = term4(aa, uu2, vv3, ej[2][3]);
            ej[3][0] = term4(aa, uu3, vv0, ej[3][0]); ej[3][1] = term4(aa, uu3, vv1, ej[3][1]);
            ej[3][2] = term4(aa, uu3, vv2, ej[3][2]); ej[3][3] = term4(aa, uu3, vv3, ej[3][3]);
        }
#pragma unroll
        for (int i = 0; i < 4; ++i)
#pragma unroll
            for (int q = 0; q < 4; ++q)
                part[eq][i][q * 64 + jj] = ej[i][q];
    }
    __syncthreads();

    // ---- combine e-quarters; finish e_ij; softmax (t = j) ----
    float e0 = part[0][0][t] + part[1][0][t] + part[2][0][t] + part[3][0][t];
    float e1 = part[0][1][t] + part[1][1][t] + part[2][1][t] + part[3][1][t];
    float e2 = part[0][2][t] + part[1][2][t] + part[2][2][t] + part[3][2][t];
    float e3 = part[0][3][t] + part[1][3][t] + part[2][3][t] + part[3][3][t];
    e0 = fmaf(0.6f, d0 + cj, e0) + ab0;
    e1 = fmaf(0.6f, d1 + cj, e1) + ab1;
    e2 = fmaf(0.6f, d2 + cj, e2) + ab2;
    e3 = fmaf(0.6f, d3 + cj, e3) + ab3;

    float m0 = e0, m1 = e1, m2 = e2, m3 = e3;
#pragma unroll
    for (int off = 32; off; off >>= 1) {
        m0 = fmaxf(m0, __shfl_xor(m0, off)); m1 = fmaxf(m1, __shfl_xor(m1, off));
        m2 = fmaxf(m2, __shfl_xor(m2, off)); m3 = fmaxf(m3, __shfl_xor(m3, off));
    }
    if (lane == 0) { redm[wave][0] = m0; redm[wave][1] = m1; redm[wave][2] = m2; redm[wave][3] = m3; }
    __syncthreads();
    m0 = fmaxf(fmaxf(redm[0][0], redm[1][0]), fmaxf(redm[2][0], redm[3][0]));
    m1 = fmaxf(fmaxf(redm[0][1], redm[1][1]), fmaxf(redm[2][1], redm[3][1]));
    m2 = fmaxf(fmaxf(redm[0][2], redm[1][2]), fmaxf(redm[2][2], redm[3][2]));
    m3 = fmaxf(fmaxf(redm[0][3], redm[1][3]), fmaxf(redm[2][3], redm[3][3]));
    float x0 = __expf(e0 - m0), x1 = __expf(e1 - m1), x2 = __expf(e2 - m2), x3 = __expf(e3 - m3);
    float s0 = x0, s1 = x1, s2 = x2, s3 = x3;
#pragma unroll
    for (int off = 32; off; off >>= 1) {
        s0 += __shfl_xor(s0, off); s1 += __shfl_xor(s1, off);
        s2 += __shfl_xor(s2, off); s3 += __shfl_xor(s3, off);
    }
    if (lane == 0) { reds[wave][0] = s0; reds[wave][1] = s1; reds[wave][2] = s2; reds[wave][3] = s3; }
    __syncthreads();
    s0 = reds[0][0] + reds[1][0] + reds[2][0] + reds[3][0];
    s1 = reds[0][1] + reds[1][1] + reds[2][1] + reds[3][1];
    s2 = reds[0][2] + reds[1][2] + reds[2][2] + reds[3][2];
    s3 = reds[0][3] + reds[1][3] + reds[2][3] + reds[3][3];
    ps[0][t] = x0 / s0;
    ps[1][t] = x1 / s1;
    ps[2][t] = x2 / s2;
    ps[3][t] = x3 / s3;
    __syncthreads();

    // ---- h-loop: thread = (jg, fq); x float4 loaded ONCE; ps read as float4 ----
    {
        const int jg = t >> 4, fq = t & 15;
        const float4* xb4 = (const float4*)x + (size_t)b * K * 16 + fq;
        const float4* ps4 = (const float4*)ps;      // [4][64]
        float4 h0 = make_float4(0,0,0,0), h1 = h0, h2 = h0, h3 = h0;
#pragma unroll
        for (int j4 = 0; j4 < 4; ++j4) {
            float4 p0 = ps4[0 * 64 + jg * 4 + j4];
            float4 p1 = ps4[1 * 64 + jg * 4 + j4];
            float4 p2 = ps4[2 * 64 + jg * 4 + j4];
            float4 p3 = ps4[3 * 64 + jg * 4 + j4];
            const int j = jg * 16 + j4 * 4;
            float4 xa = xb4[(size_t)(j + 0) * 16];
            float4 xb = xb4[(size_t)(j + 1) * 16];
            float4 xc = xb4[(size_t)(j + 2) * 16];
            float4 xd = xb4[(size_t)(j + 3) * 16];
            h0.x = fmaf(p0.x, xa.x, h0.x); h0.y = fmaf(p0.x, xa.y, h0.y); h0.z = fmaf(p0.x, xa.z, h0.z); h0.w = fmaf(p0.x, xa.w, h0.w);
            h0.x = fmaf(p0.y, xb.x, h0.x); h0.y = fmaf(p0.y, xb.y, h0.y); h0.z = fmaf(p0.y, xb.z, h0.z); h0.w = fmaf(p0.y, xb.w, h0.w);
            h0.x = fmaf(p0.z, xc.x, h0.x); h0.y = fmaf(p0.z, xc.y, h0.y); h0.z = fmaf(p0.z, xc.z, h0.z); h0.w = fmaf(p0.z, xc.w, h0.w);
            h0.x = fmaf(p0.w, xd.x, h0.x); h0.y = fmaf(p0.w, xd.y, h0.y); h0.z = fmaf(p0.w, xd.z, h0.z); h0.w = fmaf(p0.w, xd.w, h0.w);
            h1.x = fmaf(p1.x, xa.x, h1.x); h1.y = fmaf(p1.x, xa.y, h1.y); h1.z = fmaf(p1.x, xa.z, h1.z); h1.w = fmaf(p1.x, xa.w, h1.w);
            h1.x = fmaf(p1.y, xb.x, h1.x); h1.y = fmaf(p1.y, xb.y, h1.y); h1.z = fmaf(p1.y, xb.z, h1.z); h1.w = fmaf(p1.y, xb.w, h1.w);
            h1.x = fmaf(p1.z, xc.x, h1.x); h1.y = fmaf(p1.z, xc.y, h1.y); h1.z = fmaf(p1.z, xc.z, h1.z); h1.w = fmaf(p1.z, xc.w, h1.w);
            h1.x = fmaf(p1.w, xd.x, h1.x); h1.y = fmaf(p1.w, xd.y, h1.y); h1.z = fmaf(p1.w, xd.z, h1.z); h1.w = fmaf(p1.w, xd.w, h1.w);
            h2.x = fmaf(p2.x, xa.x, h2.x); h2.y = fmaf(p2.x, xa.y, h2.y); h2.z = fmaf(p2.x, xa.z, h2.z); h2.w = fmaf(p2.x, xa.w, h2.w);
            h2.x = fmaf(p2.y, xb.x, h2.x); h2.y = fmaf(p2.y, xb.y, h2.y); h2.z = fmaf(p2.y, xb.z, h2.z); h2.w = fmaf(p2.y, xb.w, h2.w);
            h2.x = fmaf(p2.z, xc.x, h2.x); h2.y = fmaf(p2.z, xc.y, h2.y); h2.z = fmaf(p2.z, xc.z, h2.z); h2.w = fmaf(p2.z, xc.w, h2.w);
            h2.x = fmaf(p2.w, xd.x, h2.x); h2.y = fmaf(p2.w, xd.y, h2.y); h2.z = fmaf(p2.w, xd.z, h2.z); h2.w = fmaf(p2.w, xd.w, h2.w);
            h3.x = fmaf(p3.x, xa.x, h3.x); h3.y = fmaf(p3.x, xa.y, h3.y); h3.z = fmaf(p3.x, xa.z, h3.z); h3.w = fmaf(p3.x, xa.w, h3.w);
            h3.x = fmaf(p3.y, xb.x, h3.x); h3.y = fmaf(p3.y, xb.y, h3.y); h3.z = fmaf(p3.y, xb.z, h3.z); h3.w = fmaf(p3.y, xb.w, h3.w);
            h3.x = fmaf(p3.z, xc.x, h3.x); h3.y = fmaf(p3.z, xc.y, h3.y); h3.z = fmaf(p3.z, xc.z, h3.z); h3.w = fmaf(p3.z, xc.w, h3.w);
            h3.x = fmaf(p3.w, xd.x, h3.x); h3.y = fmaf(p3.w, xd.y, h3.y); h3.z = fmaf(p3.w, xd.z, h3.z); h3.w = fmaf(p3.w, xd.w, h3.w);
        }
#pragma unroll
        for (int off = 16; off <= 32; off <<= 1) {
            h0.x += __shfl_xor(h0.x, off); h0.y += __shfl_xor(h0.y, off);
            h0.z += __shfl_xor(h0.z, off); h0.w += __shfl_xor(h0.w, off);
            h1.x += __shfl_xor(h1.x, off); h1.y += __shfl_xor(h1.y, off);
            h1.z += __shfl_xor(h1.z, off); h1.w += __shfl_xor(h1.w, off);
            h2.x += __shfl_xor(h2.x, off); h2.y += __shfl_xor(h2.y, off);
            h2.z += __shfl_xor(h2.z, off); h2.w += __shfl_xor(h2.w, off);
            h3.x += __shfl_xor(h3.x, off); h3.y += __shfl_xor(h3.y, off);
            h3.z += __shfl_xor(h3.z, off); h3.w += __shfl_xor(h3.w, off);
        }
        if (lane < 16) {
            hpart[wave][0][lane] = h0; hpart[wave][1][lane] = h1;
            hpart[wave][2][lane] = h2; hpart[wave][3][lane] = h3;
        }
    }
    __syncthreads();
    if (t < 64) {
        const int i = t >> 4, f4 = t & 15;
        float4 A = hpart[0][i][f4], Bq = hpart[1][i][f4];
        float4 C = hpart[2][i][f4], D = hpart[3][i][f4];
        float4 hv;
        hv.x = A.x + Bq.x + C.x + D.x; hv.y = A.y + Bq.y + C.y + D.y;
        hv.z = A.z + Bq.z + C.z + D.z; hv.w = A.w + Bq.w + C.w + D.w;
        hv.x = 1.f / (1.f + __expf(-hv.x)); hv.y = 1.f / (1.f + __expf(-hv.y));
        hv.z = 1.f / (1.f + __expf(-hv.z)); hv.w = 1.f / (1.f + __expf(-hv.w));
        h4s[i][f4] = hv;
    }
    __syncthreads();

    // ---- fc epilogue: thread = (i=wave, o=lane) ----
    {
        float acc = 0.f;
#pragma unroll
        for (int f4 = 0; f4 < 16; ++f4) {
            float4 hv = h4s[wave][f4];       // LDS broadcast
            float4 wv = fcp[f4 * 64 + lane]; // coalesced
            acc = fmaf(hv.x, wv.x, acc); acc = fmaf(hv.y, wv.y, acc);
            acc = fmaf(hv.z, wv.z, acc); acc = fmaf(hv.w, wv.w, acc);
        }
        out[(b * K + i0 + wave) * F + lane] = acc + fc_b[lane];
    }
}

extern "C" void kernel_launch(void* const* d_in, const int* in_sizes, int n_in,
                              void* d_out, int out_size, void* d_ws, size_t ws_size,
                              hipStream_t stream) {
    const float* x        = (const float*)d_in[0];
    const float* lin_w    = (const float*)d_in[1];
    const float* lin_b    = (const float*)d_in[2];
    const float* a        = (const float*)d_in[3];
    const float* att_bias = (const float*)d_in[4];
    const float* fc_w     = (const float*)d_in[5];
    const float* fc_b     = (const float*)d_in[6];
    float* out = (float*)d_out;

    float* u   = (float*)d_ws;                     // 262144 floats
    float* vT  = u + B * K * E;                    // 262144
    float* c   = vT + B * K * E;                   // 2048
    float* d   = c + B * K;                        // 2048
    float4* wq  = (float4*)(d + B * K);            // 4096 float4
    float4* fcp = wq + 32 * E;                     // 1024 float4

    gat_k0<<<20, 256, 0, stream>>>(lin_w, fc_w, wq, fcp);
    gat_k1<<<B * K / 4, 256, 0, stream>>>(x, wq, lin_b, a, u, vT, c, d);
    gat_k2<<<B * K / 4, 256, 0, stream>>>(x, a, att_bias, fcp, fc_b, u,
                                          (const float4*)vT, c, d, out);
}

// Round 8
// 28.156 us; speedup vs baseline: 1.0796x; 1.0029x over previous
//
#include <hip/hip_runtime.h>
#include <hip/hip_bf16.h>

#define ALPHA 0.2f
constexpr int B = 8, K = 256, F = 64, E = 128;   // E = 2*F

// ---------------------------------------------------------------------------
// Workspace floats:
//   u   [B*K][E]                                               262144
//   vT  float4-transposed v: f4-idx (b*32+e4)*K + k, comp e&3  262144
//   c   [B*K] = sum_e a_e*v, d [B*K] = sum_e a_e*u             2048 + 2048
//   wq  float4 [32][128] packed lin_w                          16384 fl
//   fcp float4 [16][64]  packed fc_w                           4096 fl
// ---------------------------------------------------------------------------

__device__ __forceinline__ float term4(float4 aa, float4 uu, float4 vv, float acc) {
    acc = fmaf(aa.x, fabsf(uu.x + vv.x), acc);
    acc = fmaf(aa.y, fabsf(uu.y + vv.y), acc);
    acc = fmaf(aa.z, fabsf(uu.z + vv.z), acc);
    acc = fmaf(aa.w, fabsf(uu.w + vv.w), acc);
    return acc;
}

// k0: pack weights for coalesced access (20 blocks x 256)
__global__ __launch_bounds__(256) void gat_k0(
    const float* __restrict__ lin_w, const float* __restrict__ fc_w,
    float4* __restrict__ wq, float4* __restrict__ fcp)
{
    int idx = blockIdx.x * 256 + threadIdx.x;
    if (idx < 32 * E) {                       // lin_w -> wq
        int e = idx & (E - 1), f2 = idx >> 7;
        const float* r = lin_w + e * (2 * F) + 2 * f2;
        wq[f2 * E + e] = make_float4(r[0], r[1], r[F], r[F + 1]);
    } else {                                  // fc_w -> fcp
        int k = idx - 32 * E;
        int f4 = k >> 6, o = k & 63;
        const float* r = fc_w + o * F + f4 * 4;
        fcp[k] = make_float4(r[0], r[1], r[2], r[3]);
    }
}

// k1: 512 blocks x 256 threads; thread (e, rh) computes 2 rows -> 4 rows/block.
__global__ __launch_bounds__(256) void gat_k1(
    const float* __restrict__ x, const float4* __restrict__ wq,
    const float* __restrict__ lin_b, const float* __restrict__ a,
    float* __restrict__ u, float* __restrict__ vT,
    float* __restrict__ c, float* __restrict__ d)
{
    const int t = threadIdx.x;
    const int wave = t >> 6, lane = t & 63;
    const int row0 = blockIdx.x * 4;
    const int e = t & 127, rh = t >> 7;
    const int b = row0 >> 8;

    __shared__ float xs[4 * F];
    __shared__ float redA[4][4];

    xs[t] = x[row0 * F + t];
    __syncthreads();

    const float* xr0 = &xs[(rh * 2) * F];
    const float* xr1 = &xs[(rh * 2 + 1) * F];
    float a10 = 0.f, a11 = 0.f, a20 = 0.f, a21 = 0.f;
#pragma unroll
    for (int f2 = 0; f2 < 32; ++f2) {
        float4 w = wq[f2 * E + e];           // coalesced 16B/lane, L2-shared
        float x0 = xr0[2 * f2], x1 = xr0[2 * f2 + 1];
        float y0 = xr1[2 * f2], y1 = xr1[2 * f2 + 1];
        a10 = fmaf(w.x, x0, fmaf(w.y, x1, a10));
        a20 = fmaf(w.z, x0, fmaf(w.w, x1, a20));
        a11 = fmaf(w.x, y0, fmaf(w.y, y1, a11));
        a21 = fmaf(w.z, y0, fmaf(w.w, y1, a21));
    }
    const float bb = lin_b[e], av = a[e];
    const float u0 = a10 + bb, u1 = a11 + bb;
    const int r0 = row0 + rh * 2;
    u[r0 * E + e] = u0;
    u[(r0 + 1) * E + e] = u1;
    const int kk = r0 & (K - 1);
    float* vbase = vT + ((b * 32 + (e >> 2)) * K) * 4 + (e & 3);
    vbase[kk * 4] = a20;
    vbase[(kk + 1) * 4] = a21;

    float vals[4] = {av * a20, av * u0, av * a21, av * u1};  // c0,d0,c1,d1
#pragma unroll
    for (int off = 32; off; off >>= 1) {
#pragma unroll
        for (int q = 0; q < 4; ++q) vals[q] += __shfl_xor(vals[q], off);
    }
    if (lane == 0) {
        redA[wave][0] = vals[0]; redA[wave][1] = vals[1];
        redA[wave][2] = vals[2]; redA[wave][3] = vals[3];
    }
    __syncthreads();
    if (t < 8) {
        int r = t >> 1, w = t & 1;           // row 0..3, 0=c 1=d
        int wp = (r >> 1) * 2, q = (r & 1) * 2 + w;
        float val = redA[wp][q] + redA[wp + 1][q];
        if (w == 0) c[row0 + r] = val; else d[row0 + r] = val;
    }
}

// k2: 512 blocks x 256 threads; block = (b, 4 i-rows).
// e-loop: wave = e-quarter, lane = jj; u/a read via wave-uniform global loads
// (scalar cache), no staging barrier. Softmax: wave = i-row, no max-sub,
// wave-local sum reduce. 4 barriers total.
__global__ __launch_bounds__(256) void gat_k2(
    const float* __restrict__ x, const float* __restrict__ a,
    const float* __restrict__ att_bias, const float4* __restrict__ fcp,
    const float* __restrict__ fc_b, const float* __restrict__ u,
    const float4* __restrict__ vT4, const float* __restrict__ c,
    const float* __restrict__ d, float* __restrict__ out)
{
    const int blk = blockIdx.x;
    const int b = blk >> 6;
    const int i0 = (blk & 63) * 4;
    const int t = threadIdx.x;
    const int wave = t >> 6, lane = t & 63;

    __shared__ float part[4][4][K];          // [eq][i][j] partial ej, 16 KB
    __shared__ float ps[4][K];               // softmax weights
    __shared__ float4 hpart[4][4][16];
    __shared__ float4 h4s[4][16];

    // ---- e-loop: wave eq handles e4 in [eq*8, eq*8+8); 4i x 4j per thread ----
    {
        const int eq = wave, jj = lane;
        const float4* v4  = vT4 + (size_t)b * 32 * K + (size_t)eq * 8 * K + jj;
        const float4* u4g = (const float4*)(u + (size_t)(b * K + i0) * E); // uniform
        const float4* a4g = (const float4*)a;                               // uniform
        float ej[4][4];                      // [i][jq]
#pragma unroll
        for (int i = 0; i < 4; ++i)
#pragma unroll
            for (int q = 0; q < 4; ++q) ej[i][q] = 0.f;

#pragma unroll 2
        for (int it = 0; it < 8; ++it) {
            const int e4 = eq * 8 + it;
            float4 aa  = a4g[e4];            // wave-uniform -> s_load
            float4 uu0 = u4g[0 * 32 + e4];
            float4 uu1 = u4g[1 * 32 + e4];
            float4 uu2 = u4g[2 * 32 + e4];
            float4 uu3 = u4g[3 * 32 + e4];
            float4 vv0 = v4[it * K + 0 * 64];
            float4 vv1 = v4[it * K + 1 * 64];
            float4 vv2 = v4[it * K + 2 * 64];
            float4 vv3 = v4[it * K + 3 * 64];
            ej[0][0] = term4(aa, uu0, vv0, ej[0][0]); ej[0][1] = term4(aa, uu0, vv1, ej[0][1]);
            ej[0][2] = term4(aa, uu0, vv2, ej[0][2]); ej[0][3] = term4(aa, uu0, vv3, ej[0][3]);
            ej[1][0] = term4(aa, uu1, vv0, ej[1][0]); ej[1][1] = term4(aa, uu1, vv1, ej[1][1]);
            ej[1][2] = term4(aa, uu1, vv2, ej[1][2]); ej[1][3] = term4(aa, uu1, vv3, ej[1][3]);
            ej[2][0] = term4(aa, uu2, vv0, ej[2][0]); ej[2][1] = term4(aa, uu2, vv1, ej[2][1]);
            ej[2][2] = term4(aa, uu2, vv2, ej[2][2]); ej[2][3] = term4(aa, uu2, vv3, ej[2][3]);
            ej[3][0] = term4(aa, uu3, vv0, ej[3][0]); ej[3][1] = term4(aa, uu3, vv1, ej[3][1]);
            ej[3][2] = term4(aa, uu3, vv2, ej[3][2]); ej[3][3] = term4(aa, uu3, vv3, ej[3][3]);
        }
#pragma unroll
        for (int i = 0; i < 4; ++i)
#pragma unroll
            for (int q = 0; q < 4; ++q)
                part[eq][i][q * 64 + jj] = ej[i][q];
    }
    __syncthreads();

    // ---- softmax: wave w owns row i0+w; no max-sub; wave-local sum ----
    {
        const int w = wave;
        const float dw = d[b * K + i0 + w];                 // uniform
        float ex[4], ssum = 0.f;
#pragma unroll
        for (int q = 0; q < 4; ++q) {
            const int j = q * 64 + lane;
            float s = part[0][w][j] + part[1][w][j] + part[2][w][j] + part[3][w][j];
            float cv = c[b * K + j];                        // coalesced
            float av = att_bias[(i0 + w) * K + j];          // coalesced
            float e  = fmaf(0.4f, s, fmaf(0.6f, dw + cv, av));
            ex[q] = __expf(e);
            ssum += ex[q];
        }
#pragma unroll
        for (int off = 32; off; off >>= 1) ssum += __shfl_xor(ssum, off);
        const float inv = 1.f / ssum;
#pragma unroll
        for (int q = 0; q < 4; ++q) ps[w][q * 64 + lane] = ex[q] * inv;
    }
    __syncthreads();

    // ---- h-loop: thread = (jg, fq); x float4 loaded ONCE; ps read as float4 ----
    {
        const int jg = t >> 4, fq = t & 15;
        const float4* xb4 = (const float4*)x + (size_t)b * K * 16 + fq;
        const float4* ps4 = (const float4*)ps;      // [4][64]
        float4 h0 = make_float4(0,0,0,0), h1 = h0, h2 = h0, h3 = h0;
#pragma unroll
        for (int j4 = 0; j4 < 4; ++j4) {
            float4 p0 = ps4[0 * 64 + jg * 4 + j4];
            float4 p1 = ps4[1 * 64 + jg * 4 + j4];
            float4 p2 = ps4[2 * 64 + jg * 4 + j4];
            float4 p3 = ps4[3 * 64 + jg * 4 + j4];
            const int j = jg * 16 + j4 * 4;
            float4 xa = xb4[(size_t)(j + 0) * 16];
            float4 xb = xb4[(size_t)(j + 1) * 16];
            float4 xc = xb4[(size_t)(j + 2) * 16];
            float4 xd = xb4[(size_t)(j + 3) * 16];
            h0.x = fmaf(p0.x, xa.x, h0.x); h0.y = fmaf(p0.x, xa.y, h0.y); h0.z = fmaf(p0.x, xa.z, h0.z); h0.w = fmaf(p0.x, xa.w, h0.w);
            h0.x = fmaf(p0.y, xb.x, h0.x); h0.y = fmaf(p0.y, xb.y, h0.y); h0.z = fmaf(p0.y, xb.z, h0.z); h0.w = fmaf(p0.y, xb.w, h0.w);
            h0.x = fmaf(p0.z, xc.x, h0.x); h0.y = fmaf(p0.z, xc.y, h0.y); h0.z = fmaf(p0.z, xc.z, h0.z); h0.w = fmaf(p0.z, xc.w, h0.w);
            h0.x = fmaf(p0.w, xd.x, h0.x); h0.y = fmaf(p0.w, xd.y, h0.y); h0.z = fmaf(p0.w, xd.z, h0.z); h0.w = fmaf(p0.w, xd.w, h0.w);
            h1.x = fmaf(p1.x, xa.x, h1.x); h1.y = fmaf(p1.x, xa.y, h1.y); h1.z = fmaf(p1.x, xa.z, h1.z); h1.w = fmaf(p1.x, xa.w, h1.w);
            h1.x = fmaf(p1.y, xb.x, h1.x); h1.y = fmaf(p1.y, xb.y, h1.y); h1.z = fmaf(p1.y, xb.z, h1.z); h1.w = fmaf(p1.y, xb.w, h1.w);
            h1.x = fmaf(p1.z, xc.x, h1.x); h1.y = fmaf(p1.z, xc.y, h1.y); h1.z = fmaf(p1.z, xc.z, h1.z); h1.w = fmaf(p1.z, xc.w, h1.w);
            h1.x = fmaf(p1.w, xd.x, h1.x); h1.y = fmaf(p1.w, xd.y, h1.y); h1.z = fmaf(p1.w, xd.z, h1.z); h1.w = fmaf(p1.w, xd.w, h1.w);
            h2.x = fmaf(p2.x, xa.x, h2.x); h2.y = fmaf(p2.x, xa.y, h2.y); h2.z = fmaf(p2.x, xa.z, h2.z); h2.w = fmaf(p2.x, xa.w, h2.w);
            h2.x = fmaf(p2.y, xb.x, h2.x); h2.y = fmaf(p2.y, xb.y, h2.y); h2.z = fmaf(p2.y, xb.z, h2.z); h2.w = fmaf(p2.y, xb.w, h2.w);
            h2.x = fmaf(p2.z, xc.x, h2.x); h2.y = fmaf(p2.z, xc.y, h2.y); h2.z = fmaf(p2.z, xc.z, h2.z); h2.w = fmaf(p2.z, xc.w, h2.w);
            h2.x = fmaf(p2.w, xd.x, h2.x); h2.y = fmaf(p2.w, xd.y, h2.y); h2.z = fmaf(p2.w, xd.z, h2.z); h2.w = fmaf(p2.w, xd.w, h2.w);
            h3.x = fmaf(p3.x, xa.x, h3.x); h3.y = fmaf(p3.x, xa.y, h3.y); h3.z = fmaf(p3.x, xa.z, h3.z); h3.w = fmaf(p3.x, xa.w, h3.w);
            h3.x = fmaf(p3.y, xb.x, h3.x); h3.y = fmaf(p3.y, xb.y, h3.y); h3.z = fmaf(p3.y, xb.z, h3.z); h3.w = fmaf(p3.y, xb.w, h3.w);
            h3.x = fmaf(p3.z, xc.x, h3.x); h3.y = fmaf(p3.z, xc.y, h3.y); h3.z = fmaf(p3.z, xc.z, h3.z); h3.w = fmaf(p3.z, xc.w, h3.w);
            h3.x = fmaf(p3.w, xd.x, h3.x); h3.y = fmaf(p3.w, xd.y, h3.y); h3.z = fmaf(p3.w, xd.z, h3.z); h3.w = fmaf(p3.w, xd.w, h3.w);
        }
#pragma unroll
        for (int off = 16; off <= 32; off <<= 1) {
            h0.x += __shfl_xor(h0.x, off); h0.y += __shfl_xor(h0.y, off);
            h0.z += __shfl_xor(h0.z, off); h0.w += __shfl_xor(h0.w, off);
            h1.x += __shfl_xor(h1.x, off); h1.y += __shfl_xor(h1.y, off);
            h1.z += __shfl_xor(h1.z, off); h1.w += __shfl_xor(h1.w, off);
            h2.x += __shfl_xor(h2.x, off); h2.y += __shfl_xor(h2.y, off);
            h2.z += __shfl_xor(h2.z, off); h2.w += __shfl_xor(h2.w, off);
            h3.x += __shfl_xor(h3.x, off); h3.y += __shfl_xor(h3.y, off);
            h3.z += __shfl_xor(h3.z, off); h3.w += __shfl_xor(h3.w, off);
        }
        if (lane < 16) {
            hpart[wave][0][lane] = h0; hpart[wave][1][lane] = h1;
            hpart[wave][2][lane] = h2; hpart[wave][3][lane] = h3;
        }
    }
    __syncthreads();
    if (t < 64) {
        const int i = t >> 4, f4 = t & 15;
        float4 A = hpart[0][i][f4], Bq = hpart[1][i][f4];
        float4 C = hpart[2][i][f4], D = hpart[3][i][f4];
        float4 hv;
        hv.x = A.x + Bq.x + C.x + D.x; hv.y = A.y + Bq.y + C.y + D.y;
        hv.z = A.z + Bq.z + C.z + D.z; hv.w = A.w + Bq.w + C.w + D.w;
        hv.x = 1.f / (1.f + __expf(-hv.x)); hv.y = 1.f / (1.f + __expf(-hv.y));
        hv.z = 1.f / (1.f + __expf(-hv.z)); hv.w = 1.f / (1.f + __expf(-hv.w));
        h4s[i][f4] = hv;
    }
    __syncthreads();

    // ---- fc epilogue: thread = (i=wave, o=lane) ----
    {
        float acc = 0.f;
#pragma unroll
        for (int f4 = 0; f4 < 16; ++f4) {
            float4 hv = h4s[wave][f4];       // LDS broadcast
            float4 wv = fcp[f4 * 64 + lane]; // coalesced
            acc = fmaf(hv.x, wv.x, acc); acc = fmaf(hv.y, wv.y, acc);
            acc = fmaf(hv.z, wv.z, acc); acc = fmaf(hv.w, wv.w, acc);
        }
        out[(b * K + i0 + wave) * F + lane] = acc + fc_b[lane];
    }
}

extern "C" void kernel_launch(void* const* d_in, const int* in_sizes, int n_in,
                              void* d_out, int out_size, void* d_ws, size_t ws_size,
                              hipStream_t stream) {
    const float* x        = (const float*)d_in[0];
    const float* lin_w    = (const float*)d_in[1];
    const float* lin_b    = (const float*)d_in[2];
    const float* a        = (const float*)d_in[3];
    const float* att_bias = (const float*)d_in[4];
    const float* fc_w     = (const float*)d_in[5];
    const float* fc_b     = (const float*)d_in[6];
    float* out = (float*)d_out;

    float* u   = (float*)d_ws;                     // 262144 floats
    float* vT  = u + B * K * E;                    // 262144
    float* c   = vT + B * K * E;                   // 2048
    float* d   = c + B * K;                        // 2048
    float4* wq  = (float4*)(d + B * K);            // 4096 float4
    float4* fcp = wq + 32 * E;                     // 1024 float4

    gat_k0<<<20, 256, 0, stream>>>(lin_w, fc_w, wq, fcp);
    gat_k1<<<B * K / 4, 256, 0, stream>>>(x, wq, lin_b, a, u, vT, c, d);
    gat_k2<<<B * K / 4, 256, 0, stream>>>(x, a, att_bias, fcp, fc_b, u,
                                          (const float4*)vT, c, d, out);
}

// Round 9
// 23.845 us; speedup vs baseline: 1.2747x; 1.1808x over previous
//
#include <hip/hip_runtime.h>
#include <hip/hip_bf16.h>

#define ALPHA 0.2f
constexpr int B = 8, K = 256, F = 64, E = 128;   // E = 2*F

// ---------------------------------------------------------------------------
// Workspace floats:
//   u   [B*K][E]                                               262144
//   vT  float4-transposed v: f4-idx (b*32+e4)*K + k, comp e&3  262144
//   c   [B*K] = sum_e a_e*v, d [B*K] = sum_e a_e*u             2048 + 2048
//   fcp float4 [16][64]  packed fc_w (written by kA block 0)   4096 fl
// ---------------------------------------------------------------------------

__device__ __forceinline__ float term4(float4 aa, float4 uu, float4 vv, float acc) {
    acc = fmaf(aa.x, fabsf(uu.x + vv.x), acc);
    acc = fmaf(aa.y, fabsf(uu.y + vv.y), acc);
    acc = fmaf(aa.z, fabsf(uu.z + vv.z), acc);
    acc = fmaf(aa.w, fabsf(uu.w + vv.w), acc);
    return acc;
}

// kA: 512 blocks x 256 threads. Stages lin_w (64 KB) into LDS with a
// per-row XOR swizzle (coalesced global reads, bank-floor LDS on both sides),
// then computes u, vT, c, d for 4 rows. Block 0 additionally packs fcp.
__global__ __launch_bounds__(256) void gat_kA(
    const float* __restrict__ x, const float* __restrict__ lin_w,
    const float* __restrict__ lin_b, const float* __restrict__ a,
    const float* __restrict__ fc_w,
    float* __restrict__ u, float* __restrict__ vT,
    float* __restrict__ c, float* __restrict__ d,
    float4* __restrict__ fcp)
{
    const int t = threadIdx.x;
    const int wave = t >> 6, lane = t & 63;
    const int row0 = blockIdx.x * 4;
    const int e = t & 127, rh = t >> 7;
    const int b = row0 >> 8;

    __shared__ float4 wls[4096];             // lin_w, per-row xor-swizzled, 64 KB
    __shared__ alignas(16) float xs[4 * F];
    __shared__ float redA[4][4];

    // ---- stage lin_w -> LDS: linear coalesced read, swizzled b128 write ----
    const float4* lw4 = (const float4*)lin_w;
#pragma unroll
    for (int i = 0; i < 16; ++i) {
        int idx = i * 256 + t;               // coalesced
        int ee = idx >> 5, cc = idx & 31;    // row e, col-f4 c
        wls[(ee << 5) | (cc ^ (ee & 31))] = lw4[idx];
    }
    xs[t] = x[row0 * F + t];

    if (blockIdx.x == 0) {                   // pack fc_w -> fcp (global)
#pragma unroll
        for (int i = 0; i < 4; ++i) {
            int k = i * 256 + t;
            int f4 = k >> 6, o = k & 63;
            const float* r = fc_w + o * F + f4 * 4;
            fcp[k] = make_float4(r[0], r[1], r[2], r[3]);
        }
    }
    __syncthreads();

    // ---- main loop: thread (e, rh) computes 2 rows; w1/w2 from swizzled LDS ----
    const int ebase = e << 5, ex = e & 31;
    const float* xr0 = &xs[(rh * 2) * F];
    const float* xr1 = &xs[(rh * 2 + 1) * F];
    float a10 = 0.f, a11 = 0.f, a20 = 0.f, a21 = 0.f;
#pragma unroll
    for (int p = 0; p < 16; ++p) {
        float4 w1 = wls[ebase + (p ^ ex)];          // lin_w[e][4p..4p+3]
        float4 w2 = wls[ebase + ((16 | p) ^ ex)];   // lin_w[e][64+4p..]
        float4 xv0 = *(const float4*)&xr0[4 * p];   // broadcast
        float4 xv1 = *(const float4*)&xr1[4 * p];   // broadcast
        a10 = fmaf(w1.x, xv0.x, a10); a10 = fmaf(w1.y, xv0.y, a10);
        a10 = fmaf(w1.z, xv0.z, a10); a10 = fmaf(w1.w, xv0.w, a10);
        a20 = fmaf(w2.x, xv0.x, a20); a20 = fmaf(w2.y, xv0.y, a20);
        a20 = fmaf(w2.z, xv0.z, a20); a20 = fmaf(w2.w, xv0.w, a20);
        a11 = fmaf(w1.x, xv1.x, a11); a11 = fmaf(w1.y, xv1.y, a11);
        a11 = fmaf(w1.z, xv1.z, a11); a11 = fmaf(w1.w, xv1.w, a11);
        a21 = fmaf(w2.x, xv1.x, a21); a21 = fmaf(w2.y, xv1.y, a21);
        a21 = fmaf(w2.z, xv1.z, a21); a21 = fmaf(w2.w, xv1.w, a21);
    }
    const float bb = lin_b[e], av = a[e];
    const float u0 = a10 + bb, u1 = a11 + bb;
    const int r0 = row0 + rh * 2;
    u[r0 * E + e] = u0;
    u[(r0 + 1) * E + e] = u1;
    const int kk = r0 & (K - 1);
    float* vbase = vT + ((b * 32 + (e >> 2)) * K) * 4 + (e & 3);
    vbase[kk * 4] = a20;
    vbase[(kk + 1) * 4] = a21;

    float vals[4] = {av * a20, av * u0, av * a21, av * u1};  // c0,d0,c1,d1
#pragma unroll
    for (int off = 32; off; off >>= 1) {
#pragma unroll
        for (int q = 0; q < 4; ++q) vals[q] += __shfl_xor(vals[q], off);
    }
    if (lane == 0) {
        redA[wave][0] = vals[0]; redA[wave][1] = vals[1];
        redA[wave][2] = vals[2]; redA[wave][3] = vals[3];
    }
    __syncthreads();
    if (t < 8) {
        int r = t >> 1, w = t & 1;           // row 0..3, 0=c 1=d
        int wp = (r >> 1) * 2, q = (r & 1) * 2 + w;
        float val = redA[wp][q] + redA[wp + 1][q];
        if (w == 0) c[row0 + r] = val; else d[row0 + r] = val;
    }
}

// kB: 512 blocks x 256 threads; block = (b, 4 i-rows). (r8 k2 unchanged)
__global__ __launch_bounds__(256) void gat_kB(
    const float* __restrict__ x, const float* __restrict__ a,
    const float* __restrict__ att_bias, const float4* __restrict__ fcp,
    const float* __restrict__ fc_b, const float* __restrict__ u,
    const float4* __restrict__ vT4, const float* __restrict__ c,
    const float* __restrict__ d, float* __restrict__ out)
{
    const int blk = blockIdx.x;
    const int b = blk >> 6;
    const int i0 = (blk & 63) * 4;
    const int t = threadIdx.x;
    const int wave = t >> 6, lane = t & 63;

    __shared__ float part[4][4][K];          // [eq][i][j] partial ej, 16 KB
    __shared__ float ps[4][K];               // softmax weights
    __shared__ float4 hpart[4][4][16];
    __shared__ float4 h4s[4][16];

    // ---- e-loop: wave eq handles e4 in [eq*8, eq*8+8); 4i x 4j per thread ----
    {
        const int eq = wave, jj = lane;
        const float4* v4  = vT4 + (size_t)b * 32 * K + (size_t)eq * 8 * K + jj;
        const float4* u4g = (const float4*)(u + (size_t)(b * K + i0) * E); // uniform
        const float4* a4g = (const float4*)a;                               // uniform
        float ej[4][4];                      // [i][jq]
#pragma unroll
        for (int i = 0; i < 4; ++i)
#pragma unroll
            for (int q = 0; q < 4; ++q) ej[i][q] = 0.f;

#pragma unroll 2
        for (int it = 0; it < 8; ++it) {
            const int e4 = eq * 8 + it;
            float4 aa  = a4g[e4];            // wave-uniform -> s_load
            float4 uu0 = u4g[0 * 32 + e4];
            float4 uu1 = u4g[1 * 32 + e4];
            float4 uu2 = u4g[2 * 32 + e4];
            float4 uu3 = u4g[3 * 32 + e4];
            float4 vv0 = v4[it * K + 0 * 64];
            float4 vv1 = v4[it * K + 1 * 64];
            float4 vv2 = v4[it * K + 2 * 64];
            float4 vv3 = v4[it * K + 3 * 64];
            ej[0][0] = term4(aa, uu0, vv0, ej[0][0]); ej[0][1] = term4(aa, uu0, vv1, ej[0][1]);
            ej[0][2] = term4(aa, uu0, vv2, ej[0][2]); ej[0][3] = term4(aa, uu0, vv3, ej[0][3]);
            ej[1][0] = term4(aa, uu1, vv0, ej[1][0]); ej[1][1] = term4(aa, uu1, vv1, ej[1][1]);
            ej[1][2] = term4(aa, uu1, vv2, ej[1][2]); ej[1][3] = term4(aa, uu1, vv3, ej[1][3]);
            ej[2][0] = term4(aa, uu2, vv0, ej[2][0]); ej[2][1] = term4(aa, uu2, vv1, ej[2][1]);
            ej[2][2] = term4(aa, uu2, vv2, ej[2][2]); ej[2][3] = term4(aa, uu2, vv3, ej[2][3]);
            ej[3][0] = term4(aa, uu3, vv0, ej[3][0]); ej[3][1] = term4(aa, uu3, vv1, ej[3][1]);
            ej[3][2] = term4(aa, uu3, vv2, ej[3][2]); ej[3][3] = term4(aa, uu3, vv3, ej[3][3]);
        }
#pragma unroll
        for (int i = 0; i < 4; ++i)
#pragma unroll
            for (int q = 0; q < 4; ++q)
                part[eq][i][q * 64 + jj] = ej[i][q];
    }
    __syncthreads();

    // ---- softmax: wave w owns row i0+w; no max-sub; wave-local sum ----
    {
        const int w = wave;
        const float dw = d[b * K + i0 + w];                 // uniform
        float ex[4], ssum = 0.f;
#pragma unroll
        for (int q = 0; q < 4; ++q) {
            const int j = q * 64 + lane;
            float s = part[0][w][j] + part[1][w][j] + part[2][w][j] + part[3][w][j];
            float cv = c[b * K + j];                        // coalesced
            float av = att_bias[(i0 + w) * K + j];          // coalesced
            float e  = fmaf(0.4f, s, fmaf(0.6f, dw + cv, av));
            ex[q] = __expf(e);
            ssum += ex[q];
        }
#pragma unroll
        for (int off = 32; off; off >>= 1) ssum += __shfl_xor(ssum, off);
        const float inv = 1.f / ssum;
#pragma unroll
        for (int q = 0; q < 4; ++q) ps[w][q * 64 + lane] = ex[q] * inv;
    }
    __syncthreads();

    // ---- h-loop: thread = (jg, fq); x float4 loaded ONCE; ps read as float4 ----
    {
        const int jg = t >> 4, fq = t & 15;
        const float4* xb4 = (const float4*)x + (size_t)b * K * 16 + fq;
        const float4* ps4 = (const float4*)ps;      // [4][64]
        float4 h0 = make_float4(0,0,0,0), h1 = h0, h2 = h0, h3 = h0;
#pragma unroll
        for (int j4 = 0; j4 < 4; ++j4) {
            float4 p0 = ps4[0 * 64 + jg * 4 + j4];
            float4 p1 = ps4[1 * 64 + jg * 4 + j4];
            float4 p2 = ps4[2 * 64 + jg * 4 + j4];
            float4 p3 = ps4[3 * 64 + jg * 4 + j4];
            const int j = jg * 16 + j4 * 4;
            float4 xa = xb4[(size_t)(j + 0) * 16];
            float4 xb = xb4[(size_t)(j + 1) * 16];
            float4 xc = xb4[(size_t)(j + 2) * 16];
            float4 xd = xb4[(size_t)(j + 3) * 16];
            h0.x = fmaf(p0.x, xa.x, h0.x); h0.y = fmaf(p0.x, xa.y, h0.y); h0.z = fmaf(p0.x, xa.z, h0.z); h0.w = fmaf(p0.x, xa.w, h0.w);
            h0.x = fmaf(p0.y, xb.x, h0.x); h0.y = fmaf(p0.y, xb.y, h0.y); h0.z = fmaf(p0.y, xb.z, h0.z); h0.w = fmaf(p0.y, xb.w, h0.w);
            h0.x = fmaf(p0.z, xc.x, h0.x); h0.y = fmaf(p0.z, xc.y, h0.y); h0.z = fmaf(p0.z, xc.z, h0.z); h0.w = fmaf(p0.z, xc.w, h0.w);
            h0.x = fmaf(p0.w, xd.x, h0.x); h0.y = fmaf(p0.w, xd.y, h0.y); h0.z = fmaf(p0.w, xd.z, h0.z); h0.w = fmaf(p0.w, xd.w, h0.w);
            h1.x = fmaf(p1.x, xa.x, h1.x); h1.y = fmaf(p1.x, xa.y, h1.y); h1.z = fmaf(p1.x, xa.z, h1.z); h1.w = fmaf(p1.x, xa.w, h1.w);
            h1.x = fmaf(p1.y, xb.x, h1.x); h1.y = fmaf(p1.y, xb.y, h1.y); h1.z = fmaf(p1.y, xb.z, h1.z); h1.w = fmaf(p1.y, xb.w, h1.w);
            h1.x = fmaf(p1.z, xc.x, h1.x); h1.y = fmaf(p1.z, xc.y, h1.y); h1.z = fmaf(p1.z, xc.z, h1.z); h1.w = fmaf(p1.z, xc.w, h1.w);
            h1.x = fmaf(p1.w, xd.x, h1.x); h1.y = fmaf(p1.w, xd.y, h1.y); h1.z = fmaf(p1.w, xd.z, h1.z); h1.w = fmaf(p1.w, xd.w, h1.w);
            h2.x = fmaf(p2.x, xa.x, h2.x); h2.y = fmaf(p2.x, xa.y, h2.y); h2.z = fmaf(p2.x, xa.z, h2.z); h2.w = fmaf(p2.x, xa.w, h2.w);
            h2.x = fmaf(p2.y, xb.x, h2.x); h2.y = fmaf(p2.y, xb.y, h2.y); h2.z = fmaf(p2.y, xb.z, h2.z); h2.w = fmaf(p2.y, xb.w, h2.w);
            h2.x = fmaf(p2.z, xc.x, h2.x); h2.y = fmaf(p2.z, xc.y, h2.y); h2.z = fmaf(p2.z, xc.z, h2.z); h2.w = fmaf(p2.z, xc.w, h2.w);
            h2.x = fmaf(p2.w, xd.x, h2.x); h2.y = fmaf(p2.w, xd.y, h2.y); h2.z = fmaf(p2.w, xd.z, h2.z); h2.w = fmaf(p2.w, xd.w, h2.w);
            h3.x = fmaf(p3.x, xa.x, h3.x); h3.y = fmaf(p3.x, xa.y, h3.y); h3.z = fmaf(p3.x, xa.z, h3.z); h3.w = fmaf(p3.x, xa.w, h3.w);
            h3.x = fmaf(p3.y, xb.x, h3.x); h3.y = fmaf(p3.y, xb.y, h3.y); h3.z = fmaf(p3.y, xb.z, h3.z); h3.w = fmaf(p3.y, xb.w, h3.w);
            h3.x = fmaf(p3.z, xc.x, h3.x); h3.y = fmaf(p3.z, xc.y, h3.y); h3.z = fmaf(p3.z, xc.z, h3.z); h3.w = fmaf(p3.z, xc.w, h3.w);
            h3.x = fmaf(p3.w, xd.x, h3.x); h3.y = fmaf(p3.w, xd.y, h3.y); h3.z = fmaf(p3.w, xd.z, h3.z); h3.w = fmaf(p3.w, xd.w, h3.w);
        }
#pragma unroll
        for (int off = 16; off <= 32; off <<= 1) {
            h0.x += __shfl_xor(h0.x, off); h0.y += __shfl_xor(h0.y, off);
            h0.z += __shfl_xor(h0.z, off); h0.w += __shfl_xor(h0.w, off);
            h1.x += __shfl_xor(h1.x, off); h1.y += __shfl_xor(h1.y, off);
            h1.z += __shfl_xor(h1.z, off); h1.w += __shfl_xor(h1.w, off);
            h2.x += __shfl_xor(h2.x, off); h2.y += __shfl_xor(h2.y, off);
            h2.z += __shfl_xor(h2.z, off); h2.w += __shfl_xor(h2.w, off);
            h3.x += __shfl_xor(h3.x, off); h3.y += __shfl_xor(h3.y, off);
            h3.z += __shfl_xor(h3.z, off); h3.w += __shfl_xor(h3.w, off);
        }
        if (lane < 16) {
            hpart[wave][0][lane] = h0; hpart[wave][1][lane] = h1;
            hpart[wave][2][lane] = h2; hpart[wave][3][lane] = h3;
        }
    }
    __syncthreads();
    if (t < 64) {
        const int i = t >> 4, f4 = t & 15;
        float4 A = hpart[0][i][f4], Bq = hpart[1][i][f4];
        float4 C = hpart[2][i][f4], D = hpart[3][i][f4];
        float4 hv;
        hv.x = A.x + Bq.x + C.x + D.x; hv.y = A.y + Bq.y + C.y + D.y;
        hv.z = A.z + Bq.z + C.z + D.z; hv.w = A.w + Bq.w + C.w + D.w;
        hv.x = 1.f / (1.f + __expf(-hv.x)); hv.y = 1.f / (1.f + __expf(-hv.y));
        hv.z = 1.f / (1.f + __expf(-hv.z)); hv.w = 1.f / (1.f + __expf(-hv.w));
        h4s[i][f4] = hv;
    }
    __syncthreads();

    // ---- fc epilogue: thread = (i=wave, o=lane) ----
    {
        float acc = 0.f;
#pragma unroll
        for (int f4 = 0; f4 < 16; ++f4) {
            float4 hv = h4s[wave][f4];       // LDS broadcast
            float4 wv = fcp[f4 * 64 + lane]; // coalesced
            acc = fmaf(hv.x, wv.x, acc); acc = fmaf(hv.y, wv.y, acc);
            acc = fmaf(hv.z, wv.z, acc); acc = fmaf(hv.w, wv.w, acc);
        }
        out[(b * K + i0 + wave) * F + lane] = acc + fc_b[lane];
    }
}

extern "C" void kernel_launch(void* const* d_in, const int* in_sizes, int n_in,
                              void* d_out, int out_size, void* d_ws, size_t ws_size,
                              hipStream_t stream) {
    const float* x        = (const float*)d_in[0];
    const float* lin_w    = (const float*)d_in[1];
    const float* lin_b    = (const float*)d_in[2];
    const float* a        = (const float*)d_in[3];
    const float* att_bias = (const float*)d_in[4];
    const float* fc_w     = (const float*)d_in[5];
    const float* fc_b     = (const float*)d_in[6];
    float* out = (float*)d_out;

    float* u   = (float*)d_ws;                     // 262144 floats
    float* vT  = u + B * K * E;                    // 262144
    float* c   = vT + B * K * E;                   // 2048
    float* d   = c + B * K;                        // 2048
    float4* fcp = (float4*)(d + B * K);            // 1024 float4

    gat_kA<<<B * K / 4, 256, 0, stream>>>(x, lin_w, lin_b, a, fc_w,
                                          u, vT, c, d, fcp);
    gat_kB<<<B * K / 4, 256, 0, stream>>>(x, a, att_bias, fcp, fc_b, u,
                                          (const float4*)vT, c, d, out);
}

// Round 10
// 21.502 us; speedup vs baseline: 1.4137x; 1.1090x over previous
//
#include <hip/hip_runtime.h>
#include <hip/hip_bf16.h>

#define ALPHA 0.2f
constexpr int B = 8, K = 256, F = 64, E = 128;   // E = 2*F

// ---------------------------------------------------------------------------
// Workspace floats:
//   u   [B*K][E]                                               262144
//   vT  float4-transposed v: f4-idx (b*32+e4)*K + k, comp e&3  262144
//   c   [B*K] = sum_e a_e*v, d [B*K] = sum_e a_e*u             2048 + 2048
//   fcp float4 [16][64]  packed fc_w (written by kA block 0)   4096 fl
// ---------------------------------------------------------------------------

__device__ __forceinline__ float term4(float4 aa, float4 uu, float4 vv, float acc) {
    acc = fmaf(aa.x, fabsf(uu.x + vv.x), acc);
    acc = fmaf(aa.y, fabsf(uu.y + vv.y), acc);
    acc = fmaf(aa.z, fabsf(uu.z + vv.z), acc);
    acc = fmaf(aa.w, fabsf(uu.w + vv.w), acc);
    return acc;
}

// kA: 256 blocks x 256 threads, 8 rows/block (thread (e, rh) does 4 rows).
// lin_w staged once per block into XOR-swizzled LDS. Block 0 packs fcp.
__global__ __launch_bounds__(256) void gat_kA(
    const float* __restrict__ x, const float* __restrict__ lin_w,
    const float* __restrict__ lin_b, const float* __restrict__ a,
    const float* __restrict__ fc_w,
    float* __restrict__ u, float* __restrict__ vT,
    float* __restrict__ c, float* __restrict__ d,
    float4* __restrict__ fcp)
{
    const int t = threadIdx.x;
    const int wave = t >> 6, lane = t & 63;
    const int row0 = blockIdx.x * 8;
    const int e = t & 127, rh = t >> 7;      // rh selects rows rh*4..rh*4+3
    const int b = row0 >> 8;

    __shared__ float4 wls[4096];             // lin_w, per-row xor-swizzled, 64 KB
    __shared__ alignas(16) float xs[8 * F];  // 8 rows of x
    __shared__ float redA[4][8];

    // ---- stage lin_w -> LDS: linear coalesced read, swizzled b128 write ----
    const float4* lw4 = (const float4*)lin_w;
#pragma unroll
    for (int i = 0; i < 16; ++i) {
        int idx = i * 256 + t;               // coalesced
        int ee = idx >> 5, cc = idx & 31;
        wls[(ee << 5) | (cc ^ (ee & 31))] = lw4[idx];
    }
    xs[t]       = x[row0 * F + t];
    xs[t + 256] = x[row0 * F + t + 256];

    if (blockIdx.x == 0) {                   // pack fc_w -> fcp (global)
#pragma unroll
        for (int i = 0; i < 4; ++i) {
            int k = i * 256 + t;
            int f4 = k >> 6, o = k & 63;
            const float* r = fc_w + o * F + f4 * 4;
            fcp[k] = make_float4(r[0], r[1], r[2], r[3]);
        }
    }
    __syncthreads();

    // ---- main loop: 4 rows per thread; w1/w2 from swizzled LDS ----
    const int ebase = e << 5, ex = e & 31;
    float acc1[4] = {0, 0, 0, 0}, acc2[4] = {0, 0, 0, 0};
#pragma unroll
    for (int p = 0; p < 16; ++p) {
        float4 w1 = wls[ebase + (p ^ ex)];          // lin_w[e][4p..4p+3]
        float4 w2 = wls[ebase + ((16 | p) ^ ex)];   // lin_w[e][64+4p..]
#pragma unroll
        for (int r = 0; r < 4; ++r) {
            float4 xv = *(const float4*)&xs[(rh * 4 + r) * F + 4 * p];  // broadcast
            acc1[r] = fmaf(w1.x, xv.x, acc1[r]); acc1[r] = fmaf(w1.y, xv.y, acc1[r]);
            acc1[r] = fmaf(w1.z, xv.z, acc1[r]); acc1[r] = fmaf(w1.w, xv.w, acc1[r]);
            acc2[r] = fmaf(w2.x, xv.x, acc2[r]); acc2[r] = fmaf(w2.y, xv.y, acc2[r]);
            acc2[r] = fmaf(w2.z, xv.z, acc2[r]); acc2[r] = fmaf(w2.w, xv.w, acc2[r]);
        }
    }
    const float bb = lin_b[e], av = a[e];
    float vals[8];                           // {c,d} x 4 rows
#pragma unroll
    for (int r = 0; r < 4; ++r) {
        const float uu = acc1[r] + bb;
        const int rr = row0 + rh * 4 + r;
        u[rr * E + e] = uu;
        vT[((b * 32 + (e >> 2)) * K + (rr & (K - 1))) * 4 + (e & 3)] = acc2[r];
        vals[r * 2 + 0] = av * acc2[r];      // c partial
        vals[r * 2 + 1] = av * uu;           // d partial
    }
#pragma unroll
    for (int off = 32; off; off >>= 1) {
#pragma unroll
        for (int q = 0; q < 8; ++q) vals[q] += __shfl_xor(vals[q], off);
    }
    if (lane == 0) {
#pragma unroll
        for (int q = 0; q < 8; ++q) redA[wave][q] = vals[q];
    }
    __syncthreads();
    if (t < 16) {
        const int half = t >> 3, loc = t & 7;   // half: rows 0-3 vs 4-7
        const int r = loc >> 1, cd = loc & 1;
        float val = redA[2 * half][loc] + redA[2 * half + 1][loc];
        const int row = row0 + half * 4 + r;
        if (cd == 0) c[row] = val; else d[row] = val;
    }
}

// kB: 256 blocks x 512 threads; block = (b, 8 i-rows).
// e-loop: wave = e-eighth (16 e's), lane = jj, tile 8i x 4j; u/a via
// wave-uniform loads. Softmax: wave = i-row. h-loop: (jg, fq), 8 i-rows.
__global__ __launch_bounds__(512) void gat_kB(
    const float* __restrict__ x, const float* __restrict__ a,
    const float* __restrict__ att_bias, const float4* __restrict__ fcp,
    const float* __restrict__ fc_b, const float* __restrict__ u,
    const float4* __restrict__ vT4, const float* __restrict__ c,
    const float* __restrict__ d, float* __restrict__ out)
{
    const int blk = blockIdx.x;
    const int b = blk >> 5;
    const int i0 = (blk & 31) * 8;
    const int t = threadIdx.x;
    const int wave = t >> 6, lane = t & 63;

    __shared__ float part[8][8][K];          // [e8][i][j] partial ej, 64 KB
    __shared__ float ps[8][K];               // softmax weights, 8 KB
    __shared__ float4 hpart[8][8][16];       // 16 KB
    __shared__ float4 h4s[8][16];            // 2 KB

    // ---- e-loop: wave w handles e4 in [w*4, w*4+4); 8i x 4j per thread ----
    {
        const int jj = lane;
        const float4* v4  = vT4 + (size_t)b * 32 * K + (size_t)wave * 4 * K + jj;
        const float4* u4g = (const float4*)(u + (size_t)(b * K + i0) * E); // uniform
        const float4* a4g = (const float4*)a;                               // uniform
        float ej[8][4];
#pragma unroll
        for (int i = 0; i < 8; ++i)
#pragma unroll
            for (int q = 0; q < 4; ++q) ej[i][q] = 0.f;

#pragma unroll
        for (int it = 0; it < 4; ++it) {
            const int e4 = wave * 4 + it;
            float4 aa = a4g[e4];             // wave-uniform -> s_load
            float4 vv0 = v4[it * K + 0 * 64];
            float4 vv1 = v4[it * K + 1 * 64];
            float4 vv2 = v4[it * K + 2 * 64];
            float4 vv3 = v4[it * K + 3 * 64];
#pragma unroll
            for (int i = 0; i < 8; ++i) {
                float4 uu = u4g[i * 32 + e4];   // wave-uniform -> s_load
                ej[i][0] = term4(aa, uu, vv0, ej[i][0]);
                ej[i][1] = term4(aa, uu, vv1, ej[i][1]);
                ej[i][2] = term4(aa, uu, vv2, ej[i][2]);
                ej[i][3] = term4(aa, uu, vv3, ej[i][3]);
            }
        }
#pragma unroll
        for (int i = 0; i < 8; ++i)
#pragma unroll
            for (int q = 0; q < 4; ++q)
                part[wave][i][q * 64 + jj] = ej[i][q];
    }
    __syncthreads();

    // ---- softmax: wave w owns row i0+w; no max-sub; wave-local sum ----
    {
        const int w = wave;
        const float dw = d[b * K + i0 + w];                 // uniform
        float ex[4], ssum = 0.f;
#pragma unroll
        for (int q = 0; q < 4; ++q) {
            const int j = q * 64 + lane;
            float s = part[0][w][j] + part[1][w][j] + part[2][w][j] + part[3][w][j]
                    + part[4][w][j] + part[5][w][j] + part[6][w][j] + part[7][w][j];
            float cv = c[b * K + j];                        // coalesced
            float av = att_bias[(i0 + w) * K + j];          // coalesced
            float e  = fmaf(0.4f, s, fmaf(0.6f, dw + cv, av));
            ex[q] = __expf(e);
            ssum += ex[q];
        }
#pragma unroll
        for (int off = 32; off; off >>= 1) ssum += __shfl_xor(ssum, off);
        const float inv = 1.f / ssum;
#pragma unroll
        for (int q = 0; q < 4; ++q) ps[w][q * 64 + lane] = ex[q] * inv;
    }
    __syncthreads();

    // ---- h-loop: thread = (jg 0..31, fq 0..15); 8 j's, 8 i-rows ----
    {
        const int jg = t >> 4, fq = t & 15;
        const float4* xb4 = (const float4*)x + (size_t)b * K * 16 + fq;
        const float4* ps4 = (const float4*)ps;      // [8][64]
        float4 h[8];
#pragma unroll
        for (int i = 0; i < 8; ++i) h[i] = make_float4(0, 0, 0, 0);
#pragma unroll
        for (int m = 0; m < 2; ++m) {
            const int j = jg * 8 + m * 4;
            float4 xa = xb4[(size_t)(j + 0) * 16];
            float4 xb = xb4[(size_t)(j + 1) * 16];
            float4 xc = xb4[(size_t)(j + 2) * 16];
            float4 xd = xb4[(size_t)(j + 3) * 16];
#pragma unroll
            for (int i = 0; i < 8; ++i) {
                float4 p = ps4[i * 64 + jg * 2 + m];
                h[i].x = fmaf(p.x, xa.x, h[i].x); h[i].y = fmaf(p.x, xa.y, h[i].y);
                h[i].z = fmaf(p.x, xa.z, h[i].z); h[i].w = fmaf(p.x, xa.w, h[i].w);
                h[i].x = fmaf(p.y, xb.x, h[i].x); h[i].y = fmaf(p.y, xb.y, h[i].y);
                h[i].z = fmaf(p.y, xb.z, h[i].z); h[i].w = fmaf(p.y, xb.w, h[i].w);
                h[i].x = fmaf(p.z, xc.x, h[i].x); h[i].y = fmaf(p.z, xc.y, h[i].y);
                h[i].z = fmaf(p.z, xc.z, h[i].z); h[i].w = fmaf(p.z, xc.w, h[i].w);
                h[i].x = fmaf(p.w, xd.x, h[i].x); h[i].y = fmaf(p.w, xd.y, h[i].y);
                h[i].z = fmaf(p.w, xd.z, h[i].z); h[i].w = fmaf(p.w, xd.w, h[i].w);
            }
        }
#pragma unroll
        for (int off = 16; off <= 32; off <<= 1) {
#pragma unroll
            for (int i = 0; i < 8; ++i) {
                h[i].x += __shfl_xor(h[i].x, off); h[i].y += __shfl_xor(h[i].y, off);
                h[i].z += __shfl_xor(h[i].z, off); h[i].w += __shfl_xor(h[i].w, off);
            }
        }
        if (lane < 16) {
#pragma unroll
            for (int i = 0; i < 8; ++i) hpart[wave][i][lane] = h[i];
        }
    }
    __syncthreads();
    if (t < 128) {
        const int i = t >> 4, f4 = t & 15;
        float4 hv = make_float4(0, 0, 0, 0);
#pragma unroll
        for (int w = 0; w < 8; ++w) {
            float4 A = hpart[w][i][f4];
            hv.x += A.x; hv.y += A.y; hv.z += A.z; hv.w += A.w;
        }
        hv.x = 1.f / (1.f + __expf(-hv.x)); hv.y = 1.f / (1.f + __expf(-hv.y));
        hv.z = 1.f / (1.f + __expf(-hv.z)); hv.w = 1.f / (1.f + __expf(-hv.w));
        h4s[i][f4] = hv;
    }
    __syncthreads();

    // ---- fc epilogue: thread = (i = wave, o = lane) ----
    {
        float acc = 0.f;
#pragma unroll
        for (int f4 = 0; f4 < 16; ++f4) {
            float4 hv = h4s[wave][f4];       // LDS broadcast
            float4 wv = fcp[f4 * 64 + lane]; // coalesced
            acc = fmaf(hv.x, wv.x, acc); acc = fmaf(hv.y, wv.y, acc);
            acc = fmaf(hv.z, wv.z, acc); acc = fmaf(hv.w, wv.w, acc);
        }
        out[(b * K + i0 + wave) * F + lane] = acc + fc_b[lane];
    }
}

extern "C" void kernel_launch(void* const* d_in, const int* in_sizes, int n_in,
                              void* d_out, int out_size, void* d_ws, size_t ws_size,
                              hipStream_t stream) {
    const float* x        = (const float*)d_in[0];
    const float* lin_w    = (const float*)d_in[1];
    const float* lin_b    = (const float*)d_in[2];
    const float* a        = (const float*)d_in[3];
    const float* att_bias = (const float*)d_in[4];
    const float* fc_w     = (const float*)d_in[5];
    const float* fc_b     = (const float*)d_in[6];
    float* out = (float*)d_out;

    float* u   = (float*)d_ws;                     // 262144 floats
    float* vT  = u + B * K * E;                    // 262144
    float* c   = vT + B * K * E;                   // 2048
    float* d   = c + B * K;                        // 2048
    float4* fcp = (float4*)(d + B * K);            // 1024 float4

    gat_kA<<<B * K / 8, 256, 0, stream>>>(x, lin_w, lin_b, a, fc_w,
                                          u, vT, c, d, fcp);
    gat_kB<<<B * K / 8, 512, 0, stream>>>(x, a, att_bias, fcp, fc_b, u,
                                          (const float4*)vT, c, d, out);
}

// Round 11
// 19.571 us; speedup vs baseline: 1.5531x; 1.0986x over previous
//
#include <hip/hip_runtime.h>
#include <hip/hip_bf16.h>

#define ALPHA 0.2f
constexpr int B = 8, K = 256, F = 64, E = 128;   // E = 2*F

typedef _Float16 h2 __attribute__((ext_vector_type(2)));

union H4 { uint2 u; struct { h2 lo, hi; } p; };

__device__ __forceinline__ h2 habs2(h2 v) {
    unsigned x; __builtin_memcpy(&x, &v, 4);
    x &= 0x7FFF7FFFu;
    __builtin_memcpy(&v, &x, 4);
    return v;
}

#if __has_builtin(__builtin_amdgcn_fdot2)
#define FDOT2(a, b, c) __builtin_amdgcn_fdot2((a), (b), (c), false)
#else
#define FDOT2(a, b, c) ((c) + (float)(a)[0] * (float)(b)[0] + (float)(a)[1] * (float)(b)[1])
#endif

// ---------------------------------------------------------------------------
// Workspace:
//   u_h  [B*K][E]  _Float16                                    512 KB
//   vT_h transposed v, half: idx ((b*32+e4)*K + k)*4 + (e&3)   512 KB
//   c,d  [B*K] fp32 (exact)                                    8 KB + 8 KB
//   fcp  float4 [16][64] packed fc_w                           16 KB
//   a_h  [E] _Float16 of 0.4*a                                 256 B
// ---------------------------------------------------------------------------

// kA: 256 blocks x 512 threads, 8 rows/block (thread (e, rh) does 2 rows).
// lin_w staged once per block into XOR-swizzled LDS. Block 0 packs fcp, a_h.
__global__ __launch_bounds__(512) void gat_kA(
    const float* __restrict__ x, const float* __restrict__ lin_w,
    const float* __restrict__ lin_b, const float* __restrict__ a,
    const float* __restrict__ fc_w,
    _Float16* __restrict__ u_h, _Float16* __restrict__ vT_h,
    float* __restrict__ c, float* __restrict__ d,
    float4* __restrict__ fcp, _Float16* __restrict__ a_h)
{
    const int t = threadIdx.x;               // 0..511
    const int wave = t >> 6, lane = t & 63;
    const int row0 = blockIdx.x * 8;
    const int e = t & 127, rh = t >> 7;      // rh 0..3 -> rows rh*2, rh*2+1
    const int b = row0 >> 8;

    __shared__ float4 wls[4096];             // lin_w, per-row xor-swizzled, 64 KB
    __shared__ alignas(16) float xs[8 * F];  // 8 rows of x
    __shared__ float redA[8][4];

    // ---- stage lin_w -> LDS: linear coalesced read, swizzled b128 write ----
    const float4* lw4 = (const float4*)lin_w;
#pragma unroll
    for (int i = 0; i < 8; ++i) {
        int idx = i * 512 + t;               // coalesced
        int ee = idx >> 5, cc = idx & 31;
        wls[(ee << 5) | (cc ^ (ee & 31))] = lw4[idx];
    }
    xs[t] = x[row0 * F + t];                 // 512 floats, one per thread

    if (blockIdx.x == 0) {                   // pack fc_w -> fcp, a -> a_h
#pragma unroll
        for (int i = 0; i < 2; ++i) {
            int k = i * 512 + t;
            int f4 = k >> 6, o = k & 63;
            const float* r = fc_w + o * F + f4 * 4;
            fcp[k] = make_float4(r[0], r[1], r[2], r[3]);
        }
        if (t < 128) a_h[t] = (_Float16)(0.4f * a[t]);
    }
    __syncthreads();

    // ---- main loop: 2 rows per thread; w1/w2 from swizzled LDS ----
    const int ebase = e << 5, ex = e & 31;
    float acc1[2] = {0, 0}, acc2[2] = {0, 0};
#pragma unroll
    for (int p = 0; p < 16; ++p) {
        float4 w1 = wls[ebase + (p ^ ex)];          // lin_w[e][4p..4p+3]
        float4 w2 = wls[ebase + ((16 | p) ^ ex)];   // lin_w[e][64+4p..]
#pragma unroll
        for (int r = 0; r < 2; ++r) {
            float4 xv = *(const float4*)&xs[(rh * 2 + r) * F + 4 * p];  // broadcast
            acc1[r] = fmaf(w1.x, xv.x, acc1[r]); acc1[r] = fmaf(w1.y, xv.y, acc1[r]);
            acc1[r] = fmaf(w1.z, xv.z, acc1[r]); acc1[r] = fmaf(w1.w, xv.w, acc1[r]);
            acc2[r] = fmaf(w2.x, xv.x, acc2[r]); acc2[r] = fmaf(w2.y, xv.y, acc2[r]);
            acc2[r] = fmaf(w2.z, xv.z, acc2[r]); acc2[r] = fmaf(w2.w, xv.w, acc2[r]);
        }
    }
    const float bb = lin_b[e], av = a[e];
    float vals[4];                           // {c,d} x 2 rows
#pragma unroll
    for (int r = 0; r < 2; ++r) {
        const float uu = acc1[r] + bb;
        const int rr = row0 + rh * 2 + r;
        u_h[rr * E + e] = (_Float16)uu;
        vT_h[(((b * 32) + (e >> 2)) * K + (rr & (K - 1))) * 4 + (e & 3)] =
            (_Float16)acc2[r];
        vals[r * 2 + 0] = av * acc2[r];      // c partial (fp32 exact)
        vals[r * 2 + 1] = av * uu;           // d partial
    }
#pragma unroll
    for (int off = 32; off; off >>= 1) {
#pragma unroll
        for (int q = 0; q < 4; ++q) vals[q] += __shfl_xor(vals[q], off);
    }
    if (lane == 0) {
#pragma unroll
        for (int q = 0; q < 4; ++q) redA[wave][q] = vals[q];
    }
    __syncthreads();
    if (t < 16) {
        // t -> rh2 (2b), r (1b), cd (1b); wave pair (2*rh2, 2*rh2+1) has rh=rh2
        const int rh2 = t >> 2, r = (t >> 1) & 1, cd = t & 1;
        float val = redA[rh2 * 2][r * 2 + cd] + redA[rh2 * 2 + 1][r * 2 + cd];
        const int row = row0 + rh2 * 2 + r;
        if (cd == 0) c[row] = val; else d[row] = val;
    }
}

// kB: 256 blocks x 512 threads; block = (b, 8 i-rows).
// e-loop in packed fp16 with v_dot2_f32_f16 fp32 accumulation.
__global__ __launch_bounds__(512) void gat_kB(
    const float* __restrict__ x, const _Float16* __restrict__ a_h,
    const float* __restrict__ att_bias, const float4* __restrict__ fcp,
    const float* __restrict__ fc_b, const _Float16* __restrict__ u_h,
    const uint2* __restrict__ vTh2, const float* __restrict__ c,
    const float* __restrict__ d, float* __restrict__ out)
{
    const int blk = blockIdx.x;
    const int b = blk >> 5;
    const int i0 = (blk & 31) * 8;
    const int t = threadIdx.x;
    const int wave = t >> 6, lane = t & 63;

    __shared__ float part[8][8][K];          // [e8][i][j] partial ej, 64 KB
    __shared__ float ps[8][K];               // softmax weights, 8 KB
    __shared__ float4 hpart[8][8][16];       // 16 KB
    __shared__ float4 h4s[8][16];            // 2 KB

    // ---- e-loop: wave w handles e4 in [w*4, w*4+4); 8i x 4j per thread ----
    {
        const int jj = lane;
        const uint2* v2 = vTh2 + (size_t)b * 32 * K + (size_t)wave * 4 * K + jj;
        const uint2* u2 = (const uint2*)(u_h + (size_t)(b * K + i0) * E); // uniform
        const uint2* a2 = (const uint2*)a_h;                               // uniform
        float ej[8][4];
#pragma unroll
        for (int i = 0; i < 8; ++i)
#pragma unroll
            for (int q = 0; q < 4; ++q) ej[i][q] = 0.f;

#pragma unroll
        for (int it = 0; it < 4; ++it) {
            const int e4 = wave * 4 + it;
            H4 av; av.u = a2[e4];            // wave-uniform -> s_load
            H4 vv0, vv1, vv2, vv3;
            vv0.u = v2[it * K + 0 * 64];
            vv1.u = v2[it * K + 1 * 64];
            vv2.u = v2[it * K + 2 * 64];
            vv3.u = v2[it * K + 3 * 64];
#pragma unroll
            for (int i = 0; i < 8; ++i) {
                H4 uu; uu.u = u2[i * 32 + e4];   // wave-uniform -> s_load
                {
                    h2 t0 = habs2(uu.p.lo + vv0.p.lo), t1 = habs2(uu.p.hi + vv0.p.hi);
                    ej[i][0] = FDOT2(av.p.lo, t0, ej[i][0]);
                    ej[i][0] = FDOT2(av.p.hi, t1, ej[i][0]);
                }
                {
                    h2 t0 = habs2(uu.p.lo + vv1.p.lo), t1 = habs2(uu.p.hi + vv1.p.hi);
                    ej[i][1] = FDOT2(av.p.lo, t0, ej[i][1]);
                    ej[i][1] = FDOT2(av.p.hi, t1, ej[i][1]);
                }
                {
                    h2 t0 = habs2(uu.p.lo + vv2.p.lo), t1 = habs2(uu.p.hi + vv2.p.hi);
                    ej[i][2] = FDOT2(av.p.lo, t0, ej[i][2]);
                    ej[i][2] = FDOT2(av.p.hi, t1, ej[i][2]);
                }
                {
                    h2 t0 = habs2(uu.p.lo + vv3.p.lo), t1 = habs2(uu.p.hi + vv3.p.hi);
                    ej[i][3] = FDOT2(av.p.lo, t0, ej[i][3]);
                    ej[i][3] = FDOT2(av.p.hi, t1, ej[i][3]);
                }
            }
        }
#pragma unroll
        for (int i = 0; i < 8; ++i)
#pragma unroll
            for (int q = 0; q < 4; ++q)
                part[wave][i][q * 64 + jj] = ej[i][q];
    }
    __syncthreads();

    // ---- softmax: wave w owns row i0+w; no max-sub; wave-local sum ----
    // note: a_h already contains 0.4*a, so part is the full 0.4*sum term
    {
        const int w = wave;
        const float dw = d[b * K + i0 + w];                 // uniform
        float ex[4], ssum = 0.f;
#pragma unroll
        for (int q = 0; q < 4; ++q) {
            const int j = q * 64 + lane;
            float s = part[0][w][j] + part[1][w][j] + part[2][w][j] + part[3][w][j]
                    + part[4][w][j] + part[5][w][j] + part[6][w][j] + part[7][w][j];
            float cv = c[b * K + j];                        // coalesced
            float av = att_bias[(i0 + w) * K + j];          // coalesced
            float e  = s + fmaf(0.6f, dw + cv, av);
            ex[q] = __expf(e);
            ssum += ex[q];
        }
#pragma unroll
        for (int off = 32; off; off >>= 1) ssum += __shfl_xor(ssum, off);
        const float inv = 1.f / ssum;
#pragma unroll
        for (int q = 0; q < 4; ++q) ps[w][q * 64 + lane] = ex[q] * inv;
    }
    __syncthreads();

    // ---- h-loop: thread = (jg 0..31, fq 0..15); 8 j's, 8 i-rows ----
    {
        const int jg = t >> 4, fq = t & 15;
        const float4* xb4 = (const float4*)x + (size_t)b * K * 16 + fq;
        const float4* ps4 = (const float4*)ps;      // [8][64]
        float4 h[8];
#pragma unroll
        for (int i = 0; i < 8; ++i) h[i] = make_float4(0, 0, 0, 0);
#pragma unroll
        for (int m = 0; m < 2; ++m) {
            const int j = jg * 8 + m * 4;
            float4 xa = xb4[(size_t)(j + 0) * 16];
            float4 xb = xb4[(size_t)(j + 1) * 16];
            float4 xc = xb4[(size_t)(j + 2) * 16];
            float4 xd = xb4[(size_t)(j + 3) * 16];
#pragma unroll
            for (int i = 0; i < 8; ++i) {
                float4 p = ps4[i * 64 + jg * 2 + m];
                h[i].x = fmaf(p.x, xa.x, h[i].x); h[i].y = fmaf(p.x, xa.y, h[i].y);
                h[i].z = fmaf(p.x, xa.z, h[i].z); h[i].w = fmaf(p.x, xa.w, h[i].w);
                h[i].x = fmaf(p.y, xb.x, h[i].x); h[i].y = fmaf(p.y, xb.y, h[i].y);
                h[i].z = fmaf(p.y, xb.z, h[i].z); h[i].w = fmaf(p.y, xb.w, h[i].w);
                h[i].x = fmaf(p.z, xc.x, h[i].x); h[i].y = fmaf(p.z, xc.y, h[i].y);
                h[i].z = fmaf(p.z, xc.z, h[i].z); h[i].w = fmaf(p.z, xc.w, h[i].w);
                h[i].x = fmaf(p.w, xd.x, h[i].x); h[i].y = fmaf(p.w, xd.y, h[i].y);
                h[i].z = fmaf(p.w, xd.z, h[i].z); h[i].w = fmaf(p.w, xd.w, h[i].w);
            }
        }
#pragma unroll
        for (int off = 16; off <= 32; off <<= 1) {
#pragma unroll
            for (int i = 0; i < 8; ++i) {
                h[i].x += __shfl_xor(h[i].x, off); h[i].y += __shfl_xor(h[i].y, off);
                h[i].z += __shfl_xor(h[i].z, off); h[i].w += __shfl_xor(h[i].w, off);
            }
        }
        if (lane < 16) {
#pragma unroll
            for (int i = 0; i < 8; ++i) hpart[wave][i][lane] = h[i];
        }
    }
    __syncthreads();
    if (t < 128) {
        const int i = t >> 4, f4 = t & 15;
        float4 hv = make_float4(0, 0, 0, 0);
#pragma unroll
        for (int w = 0; w < 8; ++w) {
            float4 A = hpart[w][i][f4];
            hv.x += A.x; hv.y += A.y; hv.z += A.z; hv.w += A.w;
        }
        hv.x = 1.f / (1.f + __expf(-hv.x)); hv.y = 1.f / (1.f + __expf(-hv.y));
        hv.z = 1.f / (1.f + __expf(-hv.z)); hv.w = 1.f / (1.f + __expf(-hv.w));
        h4s[i][f4] = hv;
    }
    __syncthreads();

    // ---- fc epilogue: thread = (i = wave, o = lane) ----
    {
        float acc = 0.f;
#pragma unroll
        for (int f4 = 0; f4 < 16; ++f4) {
            float4 hv = h4s[wave][f4];       // LDS broadcast
            float4 wv = fcp[f4 * 64 + lane]; // coalesced
            acc = fmaf(hv.x, wv.x, acc); acc = fmaf(hv.y, wv.y, acc);
            acc = fmaf(hv.z, wv.z, acc); acc = fmaf(hv.w, wv.w, acc);
        }
        out[(b * K + i0 + wave) * F + lane] = acc + fc_b[lane];
    }
}

extern "C" void kernel_launch(void* const* d_in, const int* in_sizes, int n_in,
                              void* d_out, int out_size, void* d_ws, size_t ws_size,
                              hipStream_t stream) {
    const float* x        = (const float*)d_in[0];
    const float* lin_w    = (const float*)d_in[1];
    const float* lin_b    = (const float*)d_in[2];
    const float* a        = (const float*)d_in[3];
    const float* att_bias = (const float*)d_in[4];
    const float* fc_w     = (const float*)d_in[5];
    const float* fc_b     = (const float*)d_in[6];
    float* out = (float*)d_out;

    _Float16* u_h  = (_Float16*)d_ws;              // 262144 halves
    _Float16* vT_h = u_h + B * K * E;              // 262144 halves
    float* c = (float*)(vT_h + B * K * E);         // 2048 fp32
    float* d = c + B * K;                          // 2048 fp32
    float4* fcp = (float4*)(d + B * K);            // 1024 float4
    _Float16* a_h = (_Float16*)(fcp + 1024);       // 128 halves

    gat_kA<<<B * K / 8, 512, 0, stream>>>(x, lin_w, lin_b, a, fc_w,
                                          u_h, vT_h, c, d, fcp, a_h);
    gat_kB<<<B * K / 8, 512, 0, stream>>>(x, a_h, att_bias, fcp, fc_b, u_h,
                                          (const uint2*)vT_h, c, d, out);
}